// Round 18
// baseline (703.423 us; speedup 1.0000x reference)
//
#include <hip/hip_runtime.h>

#define BATCH 16
#define CH 32
#define DC 3
#define SS 128
#define HH 255
#define RST 256                 // padded x stride per channel (f16)
#define FST ((size_t)CH*RST)    // stride per (b,y) row-group: 8192 halves
#define M1 12
#define M2 12
#define KY24 (2*M1)
#define NROWS (BATCH*CH*HH)
#define TWOPI_N 0.02463994238463573f   // 2*pi/255

typedef __attribute__((ext_vector_type(8))) _Float16 f16x8;
typedef __attribute__((ext_vector_type(4))) float f32x4;

// field layout: [b][y][c][x]  (c-inner: k_fuse/k_final blocks contiguous)

// ------- mirror + fc0 lift, vectorized f16x8 stores ------------------------
__global__ void __launch_bounds__(256) k_fc0(
    const float* __restrict__ x, const float* __restrict__ w,
    const float* __restrict__ bias, _Float16* __restrict__ h){
  int y = blockIdx.x, b = blockIdx.y, t = threadIdx.x;
  int d = t >> 3, g = t & 7;
  int iy = (y >= SS-1) ? y - (SS-1) : (SS-1) - y;
  float w0 = w[d], w1 = w[CH+d], w2 = w[2*CH+d], bs = bias[d];
  const float* xp = x + (size_t)(b*DC)*SS*SS + iy*SS;
  size_t obase = (size_t)(b*HH + y)*FST + (size_t)d*RST;
  #pragma unroll
  for (int i=0; i<4; i++){
    int x0 = i*64 + g*8;
    f16x8 pk;
    #pragma unroll
    for (int u=0; u<8; u++){
      int xx = x0 + u;
      float v = 0.f;
      if (xx < HH){
        int ix = (xx >= SS-1) ? xx - (SS-1) : (SS-1) - xx;
        float sgn = ((y >= SS-1) == (xx >= SS-1)) ? 1.f : -1.f;
        v = bs + sgn*(xp[ix]*w0 + xp[SS*SS+ix]*w1 + xp[2*SS*SS+ix]*w2);
      }
      pk[u] = (_Float16)v;
    }
    *(f16x8*)(h + obase + x0) = pk;
  }
}

// ------- all weight/twiddle tables in one kernel ---------------------------
__global__ void __launch_bounds__(256) k_tabs(
    const float* __restrict__ w1,
    _Float16* __restrict__ Whi, _Float16* __restrict__ Wlo,
    _Float16* __restrict__ Th,  _Float16* __restrict__ Tl,
    _Float16* __restrict__ W1h, _Float16* __restrict__ W1l){
  int bi = blockIdx.x;
  if (bi < 4){
    int t = bi*256 + threadIdx.x;          // t < 1024 = 2*8*64
    int ct = t >> 9, ks = (t >> 6) & 7, lane = t & 63;
    int col = ct*16 + (lane & 15);
    int kb = ks*32 + (lane >> 4)*8;
    for (int j=0; j<8; j++){
      int k = kb + j;
      float w = 0.f;
      if (k < 255 && col < 24){
        int m = col >> 1;
        float ang = TWOPI_N * (float)((k*m) % 255);
        w = (col & 1) ? -sinf(ang) : cosf(ang);
      }
      _Float16 hi = (_Float16)w;
      Whi[t*8+j] = hi;
      Wlo[t*8+j] = (_Float16)(w - (float)hi);
    }
  } else if (bi < 8){
    int t = (bi-4)*256 + threadIdx.x;      // t < 1024 = 16*64
    int ct = t >> 6, lane = t & 63;
    int xx = ct*16 + (lane & 15);
    int jbase = (lane >> 4)*8;
    for (int j=0; j<8; j++){
      int jg = jbase + j;
      float v = 0.f;
      if (xx < HH && jg <= 22){
        if (jg == 0) v = 1.f;
        else if (jg & 1){ int kx=(jg+1)>>1; v =  cosf(TWOPI_N*(float)((kx*xx)%255)); }
        else            { int kx= jg>>1;    v = -sinf(TWOPI_N*(float)((kx*xx)%255)); }
      }
      _Float16 hi = (_Float16)v;
      Th[t*8+j] = hi;
      Tl[t*8+j] = (_Float16)(v - (float)hi);
    }
  } else {
    int t = (bi-8)*256 + threadIdx.x;      // t < 512 = 8*64
    int nt = t >> 6, lane = t & 63;
    int col = nt*16 + (lane & 15);
    int kb = (lane >> 4)*8;
    for (int j=0; j<8; j++){
      float v = w1[(kb+j)*128 + col];
      _Float16 hi = (_Float16)v;
      W1h[t*8+j] = hi;
      W1l[t*8+j] = (_Float16)(v - (float)hi);
    }
  }
}

// ----- fused per-channel BN-stats + forward DFT (W via MFMA, H via recur) --
__global__ void __launch_bounds__(256) k_fwd(
    const _Float16* __restrict__ h, float* __restrict__ Xf,
    const _Float16* __restrict__ Whi, const _Float16* __restrict__ Wlo,
    const float* __restrict__ parts, const float* __restrict__ g,
    const float* __restrict__ bb, float* __restrict__ bnpo,
    int l0, int relu){
  __shared__ float lr[HH][26];           // [y][kx*2 + re/im], 26.5 KB
  __shared__ float rs[256][2];
  int t = threadIdx.x, bc = blockIdx.x;
  int wid = t >> 6, lane = t & 63;
  int c = bc & (CH-1), b = bc >> 5;
  float sc = 1.f, sh = 0.f;
  if (!l0){
    float s1 = 0.f, s2 = 0.f;
    for (int k=t; k<BATCH*HH; k+=256){
      float2 p2 = *(const float2*)(parts + (size_t)k*64 + c*2);
      s1 += p2.x; s2 += p2.y;
    }
    rs[t][0] = s1; rs[t][1] = s2;
    __syncthreads();
    for (int w2=128; w2>0; w2>>=1){
      if (t < w2){ rs[t][0] += rs[t+w2][0]; rs[t][1] += rs[t+w2][1]; }
      __syncthreads();
    }
    const float N = (float)BATCH * (float)(HH*HH);
    float mean = rs[0][0] / N;
    float var  = rs[0][1] / N - mean*mean;
    float iv = rsqrtf(var + 1e-5f);
    sc = g[c]*iv;
    sh = bb[c] - mean*sc;
    __syncthreads();
  }
  if (b == 0 && t == 0){ bnpo[c] = sc; bnpo[CH+c] = sh; }
  _Float16 sch = (_Float16)sc, shh = (_Float16)sh;
  f16x8 scv, shv;
  #pragma unroll
  for (int u=0; u<8; u++){ scv[u]=sch; shv[u]=shh; }
  const _Float16* base = h + (size_t)b*HH*FST + (size_t)c*RST;
  int koff = (lane >> 4)*8;
  #pragma unroll
  for (int it=0; it<4; it++){
    int y0 = it*64 + wid*16;
    int yr = y0 + (lane & 15);
    int ycl = (yr < HH) ? yr : HH-1;     // clamp pad row (output discarded)
    const _Float16* rp = base + (size_t)ycl*FST;
    f16x8 av[8];
    #pragma unroll
    for (int ks=0; ks<8; ks++)
      av[ks] = *(const f16x8*)(rp + ks*32 + koff);
    f32x4 acc0 = {0.f,0.f,0.f,0.f};
    f32x4 acc1 = {0.f,0.f,0.f,0.f};
    #pragma unroll
    for (int ks=0; ks<8; ks++){
      f16x8 a = av[ks]*scv + shv;
      if (relu){
        #pragma unroll
        for (int u=0; u<8; u++) a[u] = (a[u] > (_Float16)0.f) ? a[u] : (_Float16)0.f;
      }
      f16x8 b0h = *(const f16x8*)(Whi + ((size_t)(0*8+ks)*64 + lane)*8);
      f16x8 b0l = *(const f16x8*)(Wlo + ((size_t)(0*8+ks)*64 + lane)*8);
      f16x8 b1h = *(const f16x8*)(Whi + ((size_t)(1*8+ks)*64 + lane)*8);
      f16x8 b1l = *(const f16x8*)(Wlo + ((size_t)(1*8+ks)*64 + lane)*8);
      acc0 = __builtin_amdgcn_mfma_f32_16x16x32_f16(a, b0h, acc0, 0,0,0);
      acc0 = __builtin_amdgcn_mfma_f32_16x16x32_f16(a, b0l, acc0, 0,0,0);
      acc1 = __builtin_amdgcn_mfma_f32_16x16x32_f16(a, b1h, acc1, 0,0,0);
      acc1 = __builtin_amdgcn_mfma_f32_16x16x32_f16(a, b1l, acc1, 0,0,0);
    }
    int colq = lane & 15;
    int rq = y0 + (lane >> 4)*4;
    #pragma unroll
    for (int q=0; q<4; q++)
      if (rq+q < HH) lr[rq+q][colq] = acc0[q];
    if (colq < 8){
      #pragma unroll
      for (int q=0; q<4; q++)
        if (rq+q < HH) lr[rq+q][16+colq] = acc1[q];
    }
  }
  __syncthreads();
  // phase 2: column DFT, 288 items over 256 threads
  for (int p = t; p < KY24*M2; p += 256){
    int ky = p / M2, kx = p - (p/M2)*M2;
    int freq = (ky < M1) ? ky : (HH - KY24 + ky);  // 0..11 or 243..254
    float ang = TWOPI_N * (float)freq;
    float c1 = cosf(ang), s1 = sinf(ang);
    float cr=1.f, sr=0.f, ar=0.f, ai=0.f;
    for (int y=0; y<HH; y++){
      float rr = lr[y][kx*2], ri = lr[y][kx*2+1];
      ar += rr*cr + ri*sr;   // * e^{-i theta}
      ai += ri*cr - rr*sr;
      float cn = cr*c1 - sr*s1;
      sr = sr*c1 + cr*s1;
      cr = cn;
    }
    const float inv = 1.0f/255.0f;
    int o = (bc*KY24 + ky)*(M2*2) + kx*2;
    Xf[o]   = ar*inv;
    Xf[o+1] = ai*inv;
  }
}

// ------- channel mix only: Xf -> Y[b][o][ky][kx][2] ------------------------
__global__ void __launch_bounds__(256) k_mix(
    const float* __restrict__ Xf, const float* __restrict__ w,
    float* __restrict__ Y){
  int o = blockIdx.x, b = blockIdx.y, t = threadIdx.x;
  for (int m = t; m < KY24*M2; m += 256){
    int ky = m / M2, kx = m - (m/M2)*M2;
    int blk = (ky < M1) ? 0 : 1;
    int m1 = ky - blk*M1;
    const float* wp = w + (size_t)blk*(CH*CH*M1*M2*2)
                        + (size_t)o*(M1*M2*2) + m1*(M2*2) + kx*2;
    const float* xp = Xf + ((size_t)(b*CH)*KY24 + ky)*(M2*2) + kx*2;
    float ar=0.f, ai=0.f;
    for (int i=0;i<CH;i++){
      float xr = xp[0], xi = xp[1];
      float wr = wp[0], wi = wp[1];
      ar += xr*wr - xi*wi;
      ai += xr*wi + xi*wr;
      xp += KY24*M2*2;
      wp += CH*M1*M2*2;
    }
    size_t oy = ((size_t)(b*CH + o)*KY24 + ky)*(M2*2) + kx*2;
    Y[oy]   = ar;
    Y[oy+1] = ai;
  }
}

// ------- fused MFMA (1 row/block): inverse-H(in-block) + conv + inv-W ------
__global__ void __launch_bounds__(256) k_fuse(
    const _Float16* __restrict__ h, const float* __restrict__ Y,
    const float* __restrict__ cw, const float* __restrict__ cb,
    _Float16* __restrict__ tout, float* __restrict__ partials,
    const _Float16* __restrict__ Th, const _Float16* __restrict__ Tl,
    const float* __restrict__ bnp, int relu){
  __shared__ _Float16 buf[8448];   // Bf: (ct*65+lane)*8+j ; Of: o*264+xx
  __shared__ float red[CH][4][2];
  __shared__ float ldsG[CH*26];    // G rows stride 26 (pad zeroed)
  int t = threadIdx.x;
  int y = blockIdx.x, b = blockIdx.y;
  size_t hbase = (size_t)(b*HH + y)*FST;
  int cS = t >> 5, xg = t & 31;
  // --- staging loads first (fill memory pipe) ---
  f16x8 ld[4];
  #pragma unroll
  for (int it=0; it<4; it++)
    ld[it] = *(const f16x8*)(h + hbase + (size_t)(it*8 + cS)*RST + xg*8);
  int w = t >> 6, lane = t & 63;
  int arow = lane & 15, koff = (lane >> 4)*8;
  // --- conv weight A fragments (independent global loads) ---
  f16x8 a0h[2], a0l[2];
  #pragma unroll
  for (int rt=0; rt<2; rt++){
    int o = rt*16 + arow;
    #pragma unroll
    for (int j=0; j<8; j++){
      float v = cw[o*CH + koff + j];
      _Float16 hi = (_Float16)v;
      a0h[rt][j] = hi;
      a0l[rt][j] = (_Float16)(v - (float)hi);
    }
  }
  // --- phase-0: inverse-H for this y from Y -> ldsG (VALU fills bubbles) ---
  if (t < 64) ldsG[(t>>1)*26 + 24 + (t&1)] = 0.f;      // zero the pads
  {
    float ang = TWOPI_N * (float)y;
    float c1 = cosf(ang), s1 = sinf(ang);
    const float inv = 1.0f/255.0f;
    for (int p = t; p < CH*M2; p += 256){
      int o = p / M2, kx = p - (p/M2)*M2;
      const float* yp = Y + ((size_t)(b*CH + o)*KY24)*(M2*2) + kx*2;
      float ar = yp[0], ai = yp[1];                    // ky=0
      float c = c1, s = s1;
      #pragma unroll
      for (int k=1; k<=11; k++){
        float yr = yp[(size_t)k*(M2*2)],      yi = yp[(size_t)k*(M2*2)+1];
        ar += yr*c - yi*s;                             // * T_k
        ai += yr*s + yi*c;
        float zr = yp[(size_t)(24-k)*(M2*2)], zi = yp[(size_t)(24-k)*(M2*2)+1];
        ar += zr*c + zi*s;                             // * conj(T_k)
        ai += zi*c - zr*s;
        float cn = c*c1 - s*s1;
        s = s*c1 + c*s1;
        c = cn;
      }
      {
        float zr = yp[12*(M2*2)], zi = yp[12*(M2*2)+1]; // freq -12: conj(T_12)
        ar += zr*c + zi*s;
        ai += zi*c - zr*s;
      }
      float f = (kx==0) ? inv : 2.0f*inv;
      *(float2*)(ldsG + o*26 + kx*2) = make_float2(ar*f, ai*f);
    }
  }
  // --- BN + scatter staging to Bf fragments ---
  #pragma unroll
  for (int it=0; it<4; it++){
    int c = it*8 + cS;
    _Float16 sc_ = (_Float16)bnp[c], sh_ = (_Float16)bnp[CH+c];
    f16x8 scv, shv;
    #pragma unroll
    for (int u=0; u<8; u++){ scv[u]=sc_; shv[u]=sh_; }
    f16x8 z = ld[it]*scv + shv;
    if (relu){
      #pragma unroll
      for (int u=0; u<8; u++) z[u] = (z[u] > (_Float16)0.f) ? z[u] : (_Float16)0.f;
    }
    int base = ((xg>>1)*65 + ((xg&1)*8) + ((c>>3)<<4))*8 + (c&7);
    #pragma unroll
    for (int u=0; u<8; u++) buf[base + u*8] = z[u];
  }
  __syncthreads();                 // covers Bf scatter AND ldsG
  // --- spectral A fragments from ldsG ---
  f16x8 a1[2];
  #pragma unroll
  for (int rt=0; rt<2; rt++){
    int o = rt*16 + arow;
    const float* gp = ldsG + o*26;
    #pragma unroll
    for (int j=0; j<8; j++){
      int jg = koff + j;           // jg>=23: T rows zero; pad reads 0
      float v = (jg==0) ? gp[0] : gp[jg+1];
      a1[rt][j] = (_Float16)v;
    }
  }
  f32x4 acc[2][4];
  #pragma unroll
  for (int rt=0; rt<2; rt++)
    #pragma unroll
    for (int cl=0; cl<4; cl++) acc[rt][cl] = (f32x4){0.f,0.f,0.f,0.f};
  #pragma unroll
  for (int cl=0; cl<4; cl++){
    int ct = w*4 + cl;
    f16x8 bd = *(const f16x8*)(buf + ((size_t)ct*65 + lane)*8);
    f16x8 th = *(const f16x8*)(Th + ((size_t)ct*64 + lane)*8);
    f16x8 tl = *(const f16x8*)(Tl + ((size_t)ct*64 + lane)*8);
    #pragma unroll
    for (int rt=0; rt<2; rt++){
      acc[rt][cl] = __builtin_amdgcn_mfma_f32_16x16x32_f16(a0h[rt], bd, acc[rt][cl], 0,0,0);
      acc[rt][cl] = __builtin_amdgcn_mfma_f32_16x16x32_f16(a0l[rt], bd, acc[rt][cl], 0,0,0);
      acc[rt][cl] = __builtin_amdgcn_mfma_f32_16x16x32_f16(a1[rt], th, acc[rt][cl], 0,0,0);
      acc[rt][cl] = __builtin_amdgcn_mfma_f32_16x16x32_f16(a1[rt], tl, acc[rt][cl], 0,0,0);
    }
  }
  #pragma unroll
  for (int rt=0; rt<2; rt++)
    #pragma unroll
    for (int q=0; q<4; q++){
      float v1 = 0.f, v2 = 0.f;
      #pragma unroll
      for (int cl=0; cl<4; cl++){
        int xxo = (w*4 + cl)*16 + (lane & 15);
        int o = rt*16 + (lane >> 4)*4 + q;
        float v = acc[rt][cl][q] + cb[o];
        float vv = (xxo < HH) ? v : 0.f;
        v1 += vv; v2 += vv*vv;
      }
      #pragma unroll
      for (int off=8; off>0; off>>=1){
        v1 += __shfl_xor(v1, off, 16);
        v2 += __shfl_xor(v2, off, 16);
      }
      if ((lane & 15) == 0){
        int o = rt*16 + (lane >> 4)*4 + q;
        red[o][w][0] = v1;
        red[o][w][1] = v2;
      }
    }
  __syncthreads();      // all Bf reads done -> safe to overwrite buf as Of
  #pragma unroll
  for (int rt=0; rt<2; rt++)
    #pragma unroll
    for (int cl=0; cl<4; cl++){
      int xxo = (w*4 + cl)*16 + (lane & 15);
      #pragma unroll
      for (int q=0; q<4; q++){
        int o = rt*16 + (lane >> 4)*4 + q;     // C/D layout (m89)
        buf[o*264 + xxo] = (_Float16)(acc[rt][cl][q] + cb[o]);
      }
    }
  __syncthreads();
  {
    int o = t >> 3, xb = (t & 7)*32;
    #pragma unroll
    for (int v4=0; v4<4; v4++){
      f16x8 vv = *(const f16x8*)(buf + o*264 + xb + v4*8);
      *(f16x8*)(tout + hbase + (size_t)o*RST + xb + v4*8) = vv;
    }
  }
  if (t < CH*2){
    int oo = t >> 1, st = t & 1;
    float s = red[oo][0][st] + red[oo][1][st] + red[oo][2][st] + red[oo][3][st];
    partials[((size_t)b*HH + y)*64 + t] = s;
  }
}

// ------ deterministic stats reduce -> scale/shift (final layer only) -------
__global__ void __launch_bounds__(512) k_stats(
    const float* __restrict__ partials,
    const float* __restrict__ g, const float* __restrict__ bb,
    float* __restrict__ bnp){
  __shared__ float acc[512];
  int o = blockIdx.x, t = threadIdx.x;
  int half = t >> 8, j = t & 255;
  float s = 0.f;
  for (int k=j; k<BATCH*HH; k+=256) s += partials[(size_t)k*64 + o*2 + half];
  acc[t] = s;
  __syncthreads();
  for (int w2=128; w2>0; w2>>=1){
    if (j < w2) acc[t] += acc[t+w2];
    __syncthreads();
  }
  if (t == 0){
    const float N = (float)BATCH * (float)(HH*HH);
    float mean = acc[0] / N;
    float var  = acc[256] / N - mean*mean;
    float iv = rsqrtf(var + 1e-5f);
    float scv = g[o]*iv;
    bnp[o]      = scv;
    bnp[CH + o] = bb[o] - mean*scv;
  }
}

// ------- final MFMA: BN(l3) + fc1 + relu + fc2, quadrant only --------------
__global__ void __launch_bounds__(256) k_final(
    const _Float16* __restrict__ tb, const float* __restrict__ bnp,
    const _Float16* __restrict__ W1h, const _Float16* __restrict__ W1l,
    const float* __restrict__ b1, const float* __restrict__ w2,
    const float* __restrict__ b2, float* __restrict__ out){
  __shared__ _Float16 Vf[128][40];      // pixel-major, 80B row stride
  int yq = blockIdx.x, b = blockIdx.y, t = threadIdx.x;
  int y = (SS-1) + yq;
  size_t rbase = (size_t)(b*HH + y)*FST;
  for (int i=t; i<CH*SS; i+=256){
    int c = i >> 7, xx = i & 127;
    float v = (float)tb[rbase + (size_t)c*RST + (SS-1) + xx]
              * bnp[c] + bnp[CH+c];
    Vf[xx][c] = (_Float16)v;
  }
  __syncthreads();
  int w = t >> 6, lane = t & 63;
  int prow = lane & 15, koff = (lane >> 4)*8, col = lane & 15;
  f16x8 a0 = *(const f16x8*)&Vf[w*32 + prow][koff];
  f16x8 a1 = *(const f16x8*)&Vf[w*32 + 16 + prow][koff];
  float s0[4] = {0.f,0.f,0.f,0.f}, s1[4] = {0.f,0.f,0.f,0.f};
  #pragma unroll
  for (int nt=0; nt<8; nt++){
    f16x8 bh = *(const f16x8*)(W1h + ((size_t)nt*64 + lane)*8);
    f16x8 bl = *(const f16x8*)(W1l + ((size_t)nt*64 + lane)*8);
    f32x4 acc0 = {0.f,0.f,0.f,0.f}, acc1 = {0.f,0.f,0.f,0.f};
    acc0 = __builtin_amdgcn_mfma_f32_16x16x32_f16(a0, bh, acc0, 0,0,0);
    acc0 = __builtin_amdgcn_mfma_f32_16x16x32_f16(a0, bl, acc0, 0,0,0);
    acc1 = __builtin_amdgcn_mfma_f32_16x16x32_f16(a1, bh, acc1, 0,0,0);
    acc1 = __builtin_amdgcn_mfma_f32_16x16x32_f16(a1, bl, acc1, 0,0,0);
    float b1v = b1[nt*16 + col];
    float w2v = w2[nt*16 + col];
    #pragma unroll
    for (int q=0; q<4; q++){
      s0[q] += fmaxf(acc0[q] + b1v, 0.f)*w2v;
      s1[q] += fmaxf(acc1[q] + b1v, 0.f)*w2v;
    }
  }
  float o2b = b2[0];
  #pragma unroll
  for (int q=0; q<4; q++){
    float v0 = s0[q], v1 = s1[q];
    #pragma unroll
    for (int off=8; off>0; off>>=1){
      v0 += __shfl_xor(v0, off, 16);
      v1 += __shfl_xor(v1, off, 16);
    }
    if (col == (unsigned)q){           // one writer per pixel, deterministic
      int p0 = w*32 + (lane >> 4)*4 + q;
      int p1 = p0 + 16;
      float r0 = v0 + o2b, r1 = v1 + o2b;
      int ob = (b*DC)*SS*SS + yq*SS;
      #pragma unroll
      for (int cc=0; cc<DC; cc++){
        out[ob + cc*SS*SS + p0] = r0;
        out[ob + cc*SS*SS + p1] = r1;
      }
    }
  }
}

extern "C" void kernel_launch(void* const* d_in, const int* in_sizes, int n_in,
                              void* d_out, int out_size, void* d_ws, size_t ws_size,
                              hipStream_t stream) {
  (void)in_sizes; (void)n_in; (void)out_size; (void)ws_size;
  const float* x      = (const float*)d_in[0];
  const float* fc0_w  = (const float*)d_in[1];
  const float* fc0_b  = (const float*)d_in[2];
  const float* spec_w = (const float*)d_in[3];
  const float* conv_w = (const float*)d_in[4];
  const float* conv_b = (const float*)d_in[5];
  const float* bn_g   = (const float*)d_in[6];
  const float* bn_b   = (const float*)d_in[7];
  const float* fc1_w  = (const float*)d_in[8];
  const float* fc1_b  = (const float*)d_in[9];
  const float* fc2_w  = (const float*)d_in[10];
  const float* fc2_b  = (const float*)d_in[11];
  float* out = (float*)d_out;
  float* ws  = (float*)d_ws;

  // field: 16*255*32*256 f16 = 33,423,360 halves = 16,711,680 floats (~64 MiB)
  _Float16* field = (_Float16*)ws;
  float* Ybuf  = ws + 16711680;                        // 294,912
  float* Xf    = Ybuf + (size_t)BATCH*CH*KY24*M2*2;    // 294,912
  float* parts = Xf   + (size_t)BATCH*CH*KY24*M2*2;    // 261,120
  float* bnpF  = parts + (size_t)64*BATCH*HH;          // 64 (per-layer fuse BN)
  float* bnpL  = bnpF + 64;                            // 64 (final BN)
  _Float16* Whi = (_Float16*)(bnpL + 64);              // 8192 halves each
  _Float16* Wlo = Whi + 2*8*64*8;
  _Float16* Th  = Wlo + 2*8*64*8;
  _Float16* Tl  = Th  + 16*64*8;
  _Float16* W1h = Tl  + 16*64*8;                       // 4096 halves each
  _Float16* W1l = W1h + 8*64*8;

  k_tabs<<<10, 256, 0, stream>>>(fc1_w, Whi, Wlo, Th, Tl, W1h, W1l);
  k_fc0<<<dim3(HH, BATCH), 256, 0, stream>>>(x, fc0_w, fc0_b, field);

  const size_t wstride = (size_t)2*CH*CH*M1*M2*2;      // per-layer spec_w elems
  for (int l=0; l<4; l++){
    int l0 = (l == 0);
    int relu = (l >= 1);                               // ReLU after layers 0..2
    const float* gg = l0 ? bn_g : bn_g + (size_t)(l-1)*CH;
    const float* gb = l0 ? bn_b : bn_b + (size_t)(l-1)*CH;
    k_fwd <<<BATCH*CH, 256, 0, stream>>>(field, Xf, Whi, Wlo,
                                         parts, gg, gb, bnpF, l0, relu);
    k_mix <<<dim3(CH, BATCH), 256, 0, stream>>>(Xf, spec_w + (size_t)l*wstride, Ybuf);
    k_fuse<<<dim3(HH, BATCH), 256, 0, stream>>>(field, Ybuf, conv_w + l*CH*CH,
                                                conv_b + l*CH, field, parts,
                                                Th, Tl, bnpF, relu);
  }
  k_stats<<<CH, 512, 0, stream>>>(parts, bn_g + 3*CH, bn_b + 3*CH, bnpL);
  k_final<<<dim3(SS, BATCH), 256, 0, stream>>>(field, bnpL, W1h, W1l,
                                               fc1_b, fc2_w, fc2_b, out);
}

// Round 20
// 524.422 us; speedup vs baseline: 1.3413x; 1.3413x over previous
//
#include <hip/hip_runtime.h>

#define BATCH 16
#define CH 32
#define DC 3
#define SS 128
#define HH 255
#define RST 256                 // padded x stride per channel (f16)
#define FST ((size_t)CH*RST)    // stride per (b,y) row-group: 8192 halves
#define M1 12
#define M2 12
#define KY24 (2*M1)
#define NROWS (BATCH*CH*HH)
#define TWOPI_N 0.02463994238463573f   // 2*pi/255

typedef __attribute__((ext_vector_type(8))) _Float16 f16x8;
typedef __attribute__((ext_vector_type(4))) float f32x4;

// field layout: [b][y][c][x]  (c-inner: k_fuse/k_final blocks contiguous)

// ------- mirror + fc0 lift, vectorized f16x8 stores ------------------------
__global__ void __launch_bounds__(256) k_fc0(
    const float* __restrict__ x, const float* __restrict__ w,
    const float* __restrict__ bias, _Float16* __restrict__ h){
  int y = blockIdx.x, b = blockIdx.y, t = threadIdx.x;
  int d = t >> 3, g = t & 7;
  int iy = (y >= SS-1) ? y - (SS-1) : (SS-1) - y;
  float w0 = w[d], w1 = w[CH+d], w2 = w[2*CH+d], bs = bias[d];
  const float* xp = x + (size_t)(b*DC)*SS*SS + iy*SS;
  size_t obase = (size_t)(b*HH + y)*FST + (size_t)d*RST;
  #pragma unroll
  for (int i=0; i<4; i++){
    int x0 = i*64 + g*8;
    f16x8 pk;
    #pragma unroll
    for (int u=0; u<8; u++){
      int xx = x0 + u;
      float v = 0.f;
      if (xx < HH){
        int ix = (xx >= SS-1) ? xx - (SS-1) : (SS-1) - xx;
        float sgn = ((y >= SS-1) == (xx >= SS-1)) ? 1.f : -1.f;
        v = bs + sgn*(xp[ix]*w0 + xp[SS*SS+ix]*w1 + xp[2*SS*SS+ix]*w2);
      }
      pk[u] = (_Float16)v;
    }
    *(f16x8*)(h + obase + x0) = pk;
  }
}

// ------- all weight/twiddle tables in one kernel ---------------------------
__global__ void __launch_bounds__(256) k_tabs(
    const float* __restrict__ w1,
    _Float16* __restrict__ Whi, _Float16* __restrict__ Wlo,
    _Float16* __restrict__ Th,  _Float16* __restrict__ Tl,
    _Float16* __restrict__ W1h, _Float16* __restrict__ W1l){
  int bi = blockIdx.x;
  if (bi < 4){
    int t = bi*256 + threadIdx.x;          // t < 1024 = 2*8*64
    int ct = t >> 9, ks = (t >> 6) & 7, lane = t & 63;
    int col = ct*16 + (lane & 15);
    int kb = ks*32 + (lane >> 4)*8;
    for (int j=0; j<8; j++){
      int k = kb + j;
      float w = 0.f;
      if (k < 255 && col < 24){
        int m = col >> 1;
        float ang = TWOPI_N * (float)((k*m) % 255);
        w = (col & 1) ? -sinf(ang) : cosf(ang);
      }
      _Float16 hi = (_Float16)w;
      Whi[t*8+j] = hi;
      Wlo[t*8+j] = (_Float16)(w - (float)hi);
    }
  } else if (bi < 8){
    int t = (bi-4)*256 + threadIdx.x;      // t < 1024 = 16*64
    int ct = t >> 6, lane = t & 63;
    int xx = ct*16 + (lane & 15);
    int jbase = (lane >> 4)*8;
    for (int j=0; j<8; j++){
      int jg = jbase + j;
      float v = 0.f;
      if (xx < HH && jg <= 22){
        if (jg == 0) v = 1.f;
        else if (jg & 1){ int kx=(jg+1)>>1; v =  cosf(TWOPI_N*(float)((kx*xx)%255)); }
        else            { int kx= jg>>1;    v = -sinf(TWOPI_N*(float)((kx*xx)%255)); }
      }
      _Float16 hi = (_Float16)v;
      Th[t*8+j] = hi;
      Tl[t*8+j] = (_Float16)(v - (float)hi);
    }
  } else {
    int t = (bi-8)*256 + threadIdx.x;      // t < 512 = 8*64
    int nt = t >> 6, lane = t & 63;
    int col = nt*16 + (lane & 15);
    int kb = (lane >> 4)*8;
    for (int j=0; j<8; j++){
      float v = w1[(kb+j)*128 + col];
      _Float16 hi = (_Float16)v;
      W1h[t*8+j] = hi;
      W1l[t*8+j] = (_Float16)(v - (float)hi);
    }
  }
}

// ----- fused per-channel BN-stats + forward DFT (W via MFMA, H via recur) --
// one block per (b,c). Computes this channel's BN scale/shift from parts
// (fixed-order -> bitwise identical across blocks); b==0 publishes to bnpo.
__global__ void __launch_bounds__(256) k_fwd(
    const _Float16* __restrict__ h, float* __restrict__ Xf,
    const _Float16* __restrict__ Whi, const _Float16* __restrict__ Wlo,
    const float* __restrict__ parts, const float* __restrict__ g,
    const float* __restrict__ bb, float* __restrict__ bnpo,
    int l0, int relu){
  __shared__ float lr[HH][26];           // [y][kx*2 + re/im], 26.5 KB
  __shared__ float rs[256][2];
  int t = threadIdx.x, bc = blockIdx.x;
  int wid = t >> 6, lane = t & 63;
  int c = bc & (CH-1), b = bc >> 5;
  float sc = 1.f, sh = 0.f;
  if (!l0){
    float s1 = 0.f, s2 = 0.f;
    for (int k=t; k<BATCH*HH; k+=256){
      float2 p2 = *(const float2*)(parts + (size_t)k*64 + c*2);
      s1 += p2.x; s2 += p2.y;
    }
    rs[t][0] = s1; rs[t][1] = s2;
    __syncthreads();
    for (int w2=128; w2>0; w2>>=1){
      if (t < w2){ rs[t][0] += rs[t+w2][0]; rs[t][1] += rs[t+w2][1]; }
      __syncthreads();
    }
    const float N = (float)BATCH * (float)(HH*HH);
    float mean = rs[0][0] / N;
    float var  = rs[0][1] / N - mean*mean;
    float iv = rsqrtf(var + 1e-5f);
    sc = g[c]*iv;
    sh = bb[c] - mean*sc;
    __syncthreads();
  }
  if (b == 0 && t == 0){ bnpo[c] = sc; bnpo[CH+c] = sh; }
  _Float16 sch = (_Float16)sc, shh = (_Float16)sh;
  f16x8 scv, shv;
  #pragma unroll
  for (int u=0; u<8; u++){ scv[u]=sch; shv[u]=shh; }
  const _Float16* base = h + (size_t)b*HH*FST + (size_t)c*RST;
  int koff = (lane >> 4)*8;
  #pragma unroll
  for (int it=0; it<4; it++){
    int y0 = it*64 + wid*16;
    int yr = y0 + (lane & 15);
    int ycl = (yr < HH) ? yr : HH-1;     // clamp pad row (output discarded)
    const _Float16* rp = base + (size_t)ycl*FST;
    f16x8 av[8];
    #pragma unroll
    for (int ks=0; ks<8; ks++)
      av[ks] = *(const f16x8*)(rp + ks*32 + koff);
    f32x4 acc0 = {0.f,0.f,0.f,0.f};
    f32x4 acc1 = {0.f,0.f,0.f,0.f};
    #pragma unroll
    for (int ks=0; ks<8; ks++){
      f16x8 a = av[ks]*scv + shv;
      if (relu){
        #pragma unroll
        for (int u=0; u<8; u++) a[u] = (a[u] > (_Float16)0.f) ? a[u] : (_Float16)0.f;
      }
      f16x8 b0h = *(const f16x8*)(Whi + ((size_t)(0*8+ks)*64 + lane)*8);
      f16x8 b0l = *(const f16x8*)(Wlo + ((size_t)(0*8+ks)*64 + lane)*8);
      f16x8 b1h = *(const f16x8*)(Whi + ((size_t)(1*8+ks)*64 + lane)*8);
      f16x8 b1l = *(const f16x8*)(Wlo + ((size_t)(1*8+ks)*64 + lane)*8);
      acc0 = __builtin_amdgcn_mfma_f32_16x16x32_f16(a, b0h, acc0, 0,0,0);
      acc0 = __builtin_amdgcn_mfma_f32_16x16x32_f16(a, b0l, acc0, 0,0,0);
      acc1 = __builtin_amdgcn_mfma_f32_16x16x32_f16(a, b1h, acc1, 0,0,0);
      acc1 = __builtin_amdgcn_mfma_f32_16x16x32_f16(a, b1l, acc1, 0,0,0);
    }
    int colq = lane & 15;
    int rq = y0 + (lane >> 4)*4;
    #pragma unroll
    for (int q=0; q<4; q++)
      if (rq+q < HH) lr[rq+q][colq] = acc0[q];
    if (colq < 8){
      #pragma unroll
      for (int q=0; q<4; q++)
        if (rq+q < HH) lr[rq+q][16+colq] = acc1[q];
    }
  }
  __syncthreads();
  // phase 2: column DFT, 288 items over 256 threads
  for (int p = t; p < KY24*M2; p += 256){
    int ky = p / M2, kx = p - (p/M2)*M2;
    int freq = (ky < M1) ? ky : (HH - KY24 + ky);  // 0..11 or 243..254
    float ang = TWOPI_N * (float)freq;
    float c1 = cosf(ang), s1 = sinf(ang);
    float cr=1.f, sr=0.f, ar=0.f, ai=0.f;
    for (int y=0; y<HH; y++){
      float rr = lr[y][kx*2], ri = lr[y][kx*2+1];
      ar += rr*cr + ri*sr;   // * e^{-i theta}
      ai += ri*cr - rr*sr;
      float cn = cr*c1 - sr*s1;
      sr = sr*c1 + cr*s1;
      cr = cn;
    }
    const float inv = 1.0f/255.0f;
    int o = (bc*KY24 + ky)*(M2*2) + kx*2;
    Xf[o]   = ar*inv;
    Xf[o+1] = ai*inv;
  }
}

// ------- fused channel-mix + inverse along H: Xf -> G[bo][y][kx] -----------
__global__ void __launch_bounds__(256) k_specmix(
    const float* __restrict__ Xf, const float* __restrict__ w,
    float* __restrict__ G){
  __shared__ float ly[KY24][M2][2];
  int o = blockIdx.x, b = blockIdx.y, t = threadIdx.x;
  for (int m = t; m < KY24*M2; m += 256){
    int ky = m / M2, kx = m - (m/M2)*M2;
    int blk = (ky < M1) ? 0 : 1;
    int m1 = ky - blk*M1;
    const float* wp = w + (size_t)blk*(CH*CH*M1*M2*2)
                        + (size_t)o*(M1*M2*2) + m1*(M2*2) + kx*2;
    const float* xp = Xf + ((size_t)(b*CH)*KY24 + ky)*(M2*2) + kx*2;
    float ar=0.f, ai=0.f;
    for (int i=0;i<CH;i++){
      float xr = xp[0], xi = xp[1];
      float wr = wp[0], wi = wp[1];
      ar += xr*wr - xi*wi;
      ai += xr*wi + xi*wr;
      xp += KY24*M2*2;
      wp += CH*M1*M2*2;
    }
    ly[ky][kx][0] = ar;
    ly[ky][kx][1] = ai;
  }
  __syncthreads();
  const float inv = 1.0f/255.0f;
  size_t bo = (size_t)b*CH + o;
  for (int p=t; p<HH*M2; p+=256){
    int y = p/M2, kx = p - (p/M2)*M2;
    float ang = TWOPI_N * (float)y;
    float c1 = cosf(ang), s1 = sinf(ang);
    float ar = ly[0][kx][0], ai = ly[0][kx][1];
    float c = c1, s = s1;
    #pragma unroll
    for (int k=1; k<=11; k++){
      float yr = ly[k][kx][0],     yi = ly[k][kx][1];
      ar += yr*c - yi*s;                 // * T_k
      ai += yr*s + yi*c;
      float zr = ly[24-k][kx][0],  zi = ly[24-k][kx][1];
      ar += zr*c + zi*s;                 // * conj(T_k)
      ai += zi*c - zr*s;
      float cn = c*c1 - s*s1;
      s = s*c1 + c*s1;
      c = cn;
    }
    {
      float zr = ly[12][kx][0], zi = ly[12][kx][1];   // freq -12: conj(T_12)
      ar += zr*c + zi*s;
      ai += zi*c - zr*s;
    }
    float f = (kx==0) ? inv : 2.0f*inv;
    size_t og = (bo*HH + y)*(M2*2) + kx*2;
    G[og]   = ar*f;
    G[og+1] = ai*f;
  }
}

// ------- fused MFMA (1 row/block): conv + inv-W + partials -----------------
// field block-read and block-write are fully contiguous (16 KB each)
__global__ void __launch_bounds__(256) k_fuse(
    const _Float16* __restrict__ h, const float* __restrict__ G,
    const float* __restrict__ cw, const float* __restrict__ cb,
    _Float16* __restrict__ tout, float* __restrict__ partials,
    const _Float16* __restrict__ Th, const _Float16* __restrict__ Tl,
    const float* __restrict__ bnp, int relu){
  __shared__ _Float16 buf[8448];   // Bf: (ct*65+lane)*8+j ; Of: o*264+xx
  __shared__ float red[CH][4][2];
  int t = threadIdx.x;
  int y = blockIdx.x, b = blockIdx.y;
  size_t hbase = (size_t)(b*HH + y)*FST;
  int cS = t >> 5, xg = t & 31;
  f16x8 ld[4];
  #pragma unroll
  for (int it=0; it<4; it++)
    ld[it] = *(const f16x8*)(h + hbase + (size_t)(it*8 + cS)*RST + xg*8);
  int w = t >> 6, lane = t & 63;
  int arow = lane & 15, koff = (lane >> 4)*8;
  f16x8 a0h[2], a0l[2], a1[2];
  #pragma unroll
  for (int rt=0; rt<2; rt++){
    int o = rt*16 + arow;
    #pragma unroll
    for (int j=0; j<8; j++){
      float v = cw[o*CH + koff + j];
      _Float16 hi = (_Float16)v;
      a0h[rt][j] = hi;
      a0l[rt][j] = (_Float16)(v - (float)hi);
    }
    const float* gp = G + ((size_t)(b*CH+o)*HH + y)*24;
    #pragma unroll
    for (int j=0; j<8; j++){
      int jg = koff + j;                 // jg>=23: T rows are zero -> don't care
      float v = (jg==0) ? gp[0] : gp[jg+1];
      a1[rt][j] = (_Float16)v;
    }
  }
  #pragma unroll
  for (int it=0; it<4; it++){
    int c = it*8 + cS;
    _Float16 sc_ = (_Float16)bnp[c], sh_ = (_Float16)bnp[CH+c];
    f16x8 scv, shv;
    #pragma unroll
    for (int u=0; u<8; u++){ scv[u]=sc_; shv[u]=sh_; }
    f16x8 z = ld[it]*scv + shv;
    if (relu){
      #pragma unroll
      for (int u=0; u<8; u++) z[u] = (z[u] > (_Float16)0.f) ? z[u] : (_Float16)0.f;
    }
    int base = ((xg>>1)*65 + ((xg&1)*8) + ((c>>3)<<4))*8 + (c&7);
    #pragma unroll
    for (int u=0; u<8; u++) buf[base + u*8] = z[u];
  }
  __syncthreads();
  f32x4 acc[2][4];
  #pragma unroll
  for (int rt=0; rt<2; rt++)
    #pragma unroll
    for (int cl=0; cl<4; cl++) acc[rt][cl] = (f32x4){0.f,0.f,0.f,0.f};
  #pragma unroll
  for (int cl=0; cl<4; cl++){
    int ct = w*4 + cl;
    f16x8 bd = *(const f16x8*)(buf + ((size_t)ct*65 + lane)*8);
    f16x8 th = *(const f16x8*)(Th + ((size_t)ct*64 + lane)*8);
    f16x8 tl = *(const f16x8*)(Tl + ((size_t)ct*64 + lane)*8);
    #pragma unroll
    for (int rt=0; rt<2; rt++){
      acc[rt][cl] = __builtin_amdgcn_mfma_f32_16x16x32_f16(a0h[rt], bd, acc[rt][cl], 0,0,0);
      acc[rt][cl] = __builtin_amdgcn_mfma_f32_16x16x32_f16(a0l[rt], bd, acc[rt][cl], 0,0,0);
      acc[rt][cl] = __builtin_amdgcn_mfma_f32_16x16x32_f16(a1[rt], th, acc[rt][cl], 0,0,0);
      acc[rt][cl] = __builtin_amdgcn_mfma_f32_16x16x32_f16(a1[rt], tl, acc[rt][cl], 0,0,0);
    }
  }
  #pragma unroll
  for (int rt=0; rt<2; rt++)
    #pragma unroll
    for (int q=0; q<4; q++){
      float v1 = 0.f, v2 = 0.f;
      #pragma unroll
      for (int cl=0; cl<4; cl++){
        int xxo = (w*4 + cl)*16 + (lane & 15);
        int o = rt*16 + (lane >> 4)*4 + q;
        float v = acc[rt][cl][q] + cb[o];
        float vv = (xxo < HH) ? v : 0.f;
        v1 += vv; v2 += vv*vv;
      }
      #pragma unroll
      for (int off=8; off>0; off>>=1){
        v1 += __shfl_xor(v1, off, 16);
        v2 += __shfl_xor(v2, off, 16);
      }
      if ((lane & 15) == 0){
        int o = rt*16 + (lane >> 4)*4 + q;
        red[o][w][0] = v1;
        red[o][w][1] = v2;
      }
    }
  __syncthreads();      // all Bf reads done -> safe to overwrite buf as Of
  #pragma unroll
  for (int rt=0; rt<2; rt++)
    #pragma unroll
    for (int cl=0; cl<4; cl++){
      int xxo = (w*4 + cl)*16 + (lane & 15);
      #pragma unroll
      for (int q=0; q<4; q++){
        int o = rt*16 + (lane >> 4)*4 + q;     // C/D layout (m89)
        buf[o*264 + xxo] = (_Float16)(acc[rt][cl][q] + cb[o]);
      }
    }
  __syncthreads();
  {
    int o = t >> 3, xb = (t & 7)*32;
    #pragma unroll
    for (int v4=0; v4<4; v4++){
      f16x8 vv = *(const f16x8*)(buf + o*264 + xb + v4*8);
      *(f16x8*)(tout + hbase + (size_t)o*RST + xb + v4*8) = vv;
    }
  }
  if (t < CH*2){
    int oo = t >> 1, st = t & 1;
    float s = red[oo][0][st] + red[oo][1][st] + red[oo][2][st] + red[oo][3][st];
    partials[((size_t)b*HH + y)*64 + t] = s;
  }
}

// ------ deterministic stats reduce -> scale/shift (final layer only) -------
__global__ void __launch_bounds__(512) k_stats(
    const float* __restrict__ partials,
    const float* __restrict__ g, const float* __restrict__ bb,
    float* __restrict__ bnp){
  __shared__ float acc[512];
  int o = blockIdx.x, t = threadIdx.x;
  int half = t >> 8, j = t & 255;
  float s = 0.f;
  for (int k=j; k<BATCH*HH; k+=256) s += partials[(size_t)k*64 + o*2 + half];
  acc[t] = s;
  __syncthreads();
  for (int w2=128; w2>0; w2>>=1){
    if (j < w2) acc[t] += acc[t+w2];
    __syncthreads();
  }
  if (t == 0){
    const float N = (float)BATCH * (float)(HH*HH);
    float mean = acc[0] / N;
    float var  = acc[256] / N - mean*mean;
    float iv = rsqrtf(var + 1e-5f);
    float scv = g[o]*iv;
    bnp[o]      = scv;
    bnp[CH + o] = bb[o] - mean*scv;
  }
}

// ------- final MFMA: BN(l3) + fc1 + relu + fc2, quadrant only --------------
__global__ void __launch_bounds__(256) k_final(
    const _Float16* __restrict__ tb, const float* __restrict__ bnp,
    const _Float16* __restrict__ W1h, const _Float16* __restrict__ W1l,
    const float* __restrict__ b1, const float* __restrict__ w2,
    const float* __restrict__ b2, float* __restrict__ out){
  __shared__ _Float16 Vf[128][40];      // pixel-major, 80B row stride
  int yq = blockIdx.x, b = blockIdx.y, t = threadIdx.x;
  int y = (SS-1) + yq;
  size_t rbase = (size_t)(b*HH + y)*FST;
  for (int i=t; i<CH*SS; i+=256){
    int c = i >> 7, xx = i & 127;
    float v = (float)tb[rbase + (size_t)c*RST + (SS-1) + xx]
              * bnp[c] + bnp[CH+c];
    Vf[xx][c] = (_Float16)v;
  }
  __syncthreads();
  int w = t >> 6, lane = t & 63;
  int prow = lane & 15, koff = (lane >> 4)*8, col = lane & 15;
  f16x8 a0 = *(const f16x8*)&Vf[w*32 + prow][koff];
  f16x8 a1 = *(const f16x8*)&Vf[w*32 + 16 + prow][koff];
  float s0[4] = {0.f,0.f,0.f,0.f}, s1[4] = {0.f,0.f,0.f,0.f};
  #pragma unroll
  for (int nt=0; nt<8; nt++){
    f16x8 bh = *(const f16x8*)(W1h + ((size_t)nt*64 + lane)*8);
    f16x8 bl = *(const f16x8*)(W1l + ((size_t)nt*64 + lane)*8);
    f32x4 acc0 = {0.f,0.f,0.f,0.f}, acc1 = {0.f,0.f,0.f,0.f};
    acc0 = __builtin_amdgcn_mfma_f32_16x16x32_f16(a0, bh, acc0, 0,0,0);
    acc0 = __builtin_amdgcn_mfma_f32_16x16x32_f16(a0, bl, acc0, 0,0,0);
    acc1 = __builtin_amdgcn_mfma_f32_16x16x32_f16(a1, bh, acc1, 0,0,0);
    acc1 = __builtin_amdgcn_mfma_f32_16x16x32_f16(a1, bl, acc1, 0,0,0);
    float b1v = b1[nt*16 + col];
    float w2v = w2[nt*16 + col];
    #pragma unroll
    for (int q=0; q<4; q++){
      s0[q] += fmaxf(acc0[q] + b1v, 0.f)*w2v;
      s1[q] += fmaxf(acc1[q] + b1v, 0.f)*w2v;
    }
  }
  float o2b = b2[0];
  #pragma unroll
  for (int q=0; q<4; q++){
    float v0 = s0[q], v1 = s1[q];
    #pragma unroll
    for (int off=8; off>0; off>>=1){
      v0 += __shfl_xor(v0, off, 16);
      v1 += __shfl_xor(v1, off, 16);
    }
    if (col == (unsigned)q){           // one writer per pixel, deterministic
      int p0 = w*32 + (lane >> 4)*4 + q;
      int p1 = p0 + 16;
      float r0 = v0 + o2b, r1 = v1 + o2b;
      int ob = (b*DC)*SS*SS + yq*SS;
      #pragma unroll
      for (int cc=0; cc<DC; cc++){
        out[ob + cc*SS*SS + p0] = r0;
        out[ob + cc*SS*SS + p1] = r1;
      }
    }
  }
}

extern "C" void kernel_launch(void* const* d_in, const int* in_sizes, int n_in,
                              void* d_out, int out_size, void* d_ws, size_t ws_size,
                              hipStream_t stream) {
  (void)in_sizes; (void)n_in; (void)out_size; (void)ws_size;
  const float* x      = (const float*)d_in[0];
  const float* fc0_w  = (const float*)d_in[1];
  const float* fc0_b  = (const float*)d_in[2];
  const float* spec_w = (const float*)d_in[3];
  const float* conv_w = (const float*)d_in[4];
  const float* conv_b = (const float*)d_in[5];
  const float* bn_g   = (const float*)d_in[6];
  const float* bn_b   = (const float*)d_in[7];
  const float* fc1_w  = (const float*)d_in[8];
  const float* fc1_b  = (const float*)d_in[9];
  const float* fc2_w  = (const float*)d_in[10];
  const float* fc2_b  = (const float*)d_in[11];
  float* out = (float*)d_out;
  float* ws  = (float*)d_ws;

  // field: 16*255*32*256 f16 = 33,423,360 halves = 16,711,680 floats (~64 MiB)
  _Float16* field = (_Float16*)ws;
  float* Gbuf  = ws + 16711680;                        // NROWS*24 = 3,133,440
  float* Xf    = Gbuf + (size_t)NROWS*24;              // 294,912
  float* parts = Xf   + (size_t)BATCH*CH*KY24*M2*2;    // 261,120
  float* bnpF  = parts + (size_t)64*BATCH*HH;          // 64 (per-layer fuse BN)
  float* bnpL  = bnpF + 64;                            // 64 (final BN)
  _Float16* Whi = (_Float16*)(bnpL + 64);              // 8192 halves each
  _Float16* Wlo = Whi + 2*8*64*8;
  _Float16* Th  = Wlo + 2*8*64*8;
  _Float16* Tl  = Th  + 16*64*8;
  _Float16* W1h = Tl  + 16*64*8;                       // 4096 halves each
  _Float16* W1l = W1h + 8*64*8;

  k_tabs<<<10, 256, 0, stream>>>(fc1_w, Whi, Wlo, Th, Tl, W1h, W1l);
  k_fc0<<<dim3(HH, BATCH), 256, 0, stream>>>(x, fc0_w, fc0_b, field);

  const size_t wstride = (size_t)2*CH*CH*M1*M2*2;      // per-layer spec_w elems
  for (int l=0; l<4; l++){
    int l0 = (l == 0);
    int relu = (l >= 1);                               // ReLU after layers 0..2
    const float* gg = l0 ? bn_g : bn_g + (size_t)(l-1)*CH;
    const float* gb = l0 ? bn_b : bn_b + (size_t)(l-1)*CH;
    k_fwd  <<<BATCH*CH, 256, 0, stream>>>(field, Xf, Whi, Wlo,
                                          parts, gg, gb, bnpF, l0, relu);
    k_specmix<<<dim3(CH, BATCH), 256, 0, stream>>>(Xf, spec_w + (size_t)l*wstride, Gbuf);
    k_fuse <<<dim3(HH, BATCH), 256, 0, stream>>>(field, Gbuf, conv_w + l*CH*CH,
                                                 conv_b + l*CH, field, parts,
                                                 Th, Tl, bnpF, relu);
  }
  k_stats<<<CH, 512, 0, stream>>>(parts, bn_g + 3*CH, bn_b + 3*CH, bnpL);
  k_final<<<dim3(SS, BATCH), 256, 0, stream>>>(field, bnpL, W1h, W1l,
                                               fc1_b, fc2_w, fc2_b, out);
}

// Round 21
// 456.540 us; speedup vs baseline: 1.5408x; 1.1487x over previous
//
#include <hip/hip_runtime.h>

#define BATCH 16
#define CH 32
#define DC 3
#define SS 128
#define HH 255
#define RST 256                 // padded x stride per channel (f16)
#define FST ((size_t)CH*RST)    // stride per (b,y) row-group: 8192 halves
#define M1 12
#define M2 12
#define KY24 (2*M1)
#define NROWS (BATCH*CH*HH)
#define TWOPI_N 0.02463994238463573f   // 2*pi/255

typedef __attribute__((ext_vector_type(8))) _Float16 f16x8;
typedef __attribute__((ext_vector_type(4))) float f32x4;

// field layout: [b][y][c][x]  (c-inner: k_fuse/k_final blocks contiguous)

// ------- mirror + fc0 lift, vectorized f16x8 stores ------------------------
__global__ void __launch_bounds__(256) k_fc0(
    const float* __restrict__ x, const float* __restrict__ w,
    const float* __restrict__ bias, _Float16* __restrict__ h){
  int y = blockIdx.x, b = blockIdx.y, t = threadIdx.x;
  int d = t >> 3, g = t & 7;
  int iy = (y >= SS-1) ? y - (SS-1) : (SS-1) - y;
  float w0 = w[d], w1 = w[CH+d], w2 = w[2*CH+d], bs = bias[d];
  const float* xp = x + (size_t)(b*DC)*SS*SS + iy*SS;
  size_t obase = (size_t)(b*HH + y)*FST + (size_t)d*RST;
  #pragma unroll
  for (int i=0; i<4; i++){
    int x0 = i*64 + g*8;
    f16x8 pk;
    #pragma unroll
    for (int u=0; u<8; u++){
      int xx = x0 + u;
      float v = 0.f;
      if (xx < HH){
        int ix = (xx >= SS-1) ? xx - (SS-1) : (SS-1) - xx;
        float sgn = ((y >= SS-1) == (xx >= SS-1)) ? 1.f : -1.f;
        v = bs + sgn*(xp[ix]*w0 + xp[SS*SS+ix]*w1 + xp[2*SS*SS+ix]*w2);
      }
      pk[u] = (_Float16)v;
    }
    *(f16x8*)(h + obase + x0) = pk;
  }
}

// ------- all weight/twiddle tables in one kernel ---------------------------
// 0-3: W (fwd row-DFT B)  4-7: T (fuse inv-W B)  8-9: W1 (final B)
// 10-13: Ac (fwd col-DFT A, cos)  14-17: As (sin)
__global__ void __launch_bounds__(256) k_tabs(
    const float* __restrict__ w1,
    _Float16* __restrict__ Whi, _Float16* __restrict__ Wlo,
    _Float16* __restrict__ Th,  _Float16* __restrict__ Tl,
    _Float16* __restrict__ W1h, _Float16* __restrict__ W1l,
    _Float16* __restrict__ Ach, _Float16* __restrict__ Acl,
    _Float16* __restrict__ Ash, _Float16* __restrict__ Asl){
  int bi = blockIdx.x;
  if (bi < 4){
    int t = bi*256 + threadIdx.x;          // t < 1024 = 2*8*64
    int ct = t >> 9, ks = (t >> 6) & 7, lane = t & 63;
    int col = ct*16 + (lane & 15);
    int kb = ks*32 + (lane >> 4)*8;
    for (int j=0; j<8; j++){
      int k = kb + j;
      float w = 0.f;
      if (k < 255 && col < 24){
        int m = col >> 1;
        float ang = TWOPI_N * (float)((k*m) % 255);
        w = (col & 1) ? -sinf(ang) : cosf(ang);
      }
      _Float16 hi = (_Float16)w;
      Whi[t*8+j] = hi;
      Wlo[t*8+j] = (_Float16)(w - (float)hi);
    }
  } else if (bi < 8){
    int t = (bi-4)*256 + threadIdx.x;      // t < 1024 = 16*64
    int ct = t >> 6, lane = t & 63;
    int xx = ct*16 + (lane & 15);
    int jbase = (lane >> 4)*8;
    for (int j=0; j<8; j++){
      int jg = jbase + j;
      float v = 0.f;
      if (xx < HH && jg <= 22){
        if (jg == 0) v = 1.f;
        else if (jg & 1){ int kx=(jg+1)>>1; v =  cosf(TWOPI_N*(float)((kx*xx)%255)); }
        else            { int kx= jg>>1;    v = -sinf(TWOPI_N*(float)((kx*xx)%255)); }
      }
      _Float16 hi = (_Float16)v;
      Th[t*8+j] = hi;
      Tl[t*8+j] = (_Float16)(v - (float)hi);
    }
  } else if (bi < 10){
    int t = (bi-8)*256 + threadIdx.x;      // t < 512 = 8*64
    int nt = t >> 6, lane = t & 63;
    int col = nt*16 + (lane & 15);
    int kb = (lane >> 4)*8;
    for (int j=0; j<8; j++){
      float v = w1[(kb+j)*128 + col];
      _Float16 hi = (_Float16)v;
      W1h[t*8+j] = hi;
      W1l[t*8+j] = (_Float16)(v - (float)hi);
    }
  } else if (bi < 14){
    int t = (bi-10)*256 + threadIdx.x;     // t < 1024 = 2*8*64
    int mt = t >> 9, ks = (t >> 6) & 7, lane = t & 63;
    int ky = mt*16 + (lane & 15);
    int yb = ks*32 + (lane >> 4)*8;
    int freq = (ky < M1) ? ky : 231 + ky;  // 0..11 / 243..254
    for (int j=0; j<8; j++){
      int yy = yb + j;
      float v = 0.f;
      if (ky < KY24 && yy < HH)
        v = cosf(TWOPI_N * (float)((freq*yy) % 255));
      _Float16 hi = (_Float16)v;
      Ach[t*8+j] = hi;
      Acl[t*8+j] = (_Float16)(v - (float)hi);
    }
  } else {
    int t = (bi-14)*256 + threadIdx.x;     // t < 1024
    int mt = t >> 9, ks = (t >> 6) & 7, lane = t & 63;
    int ky = mt*16 + (lane & 15);
    int yb = ks*32 + (lane >> 4)*8;
    int freq = (ky < M1) ? ky : 231 + ky;
    for (int j=0; j<8; j++){
      int yy = yb + j;
      float v = 0.f;
      if (ky < KY24 && yy < HH)
        v = sinf(TWOPI_N * (float)((freq*yy) % 255));
      _Float16 hi = (_Float16)v;
      Ash[t*8+j] = hi;
      Asl[t*8+j] = (_Float16)(v - (float)hi);
    }
  }
}

// ----- fused per-channel BN-stats + forward DFT (both axes via MFMA) -------
// one block per (b,c). BN scale/shift from parts (fixed-order, bitwise
// identical across blocks); b==0 publishes to bnpo. Phase 2 = two real
// GEMMs (cos/sin) over precomputed A tables, recombined via shfl_xor.
__global__ void __launch_bounds__(256) k_fwd(
    const _Float16* __restrict__ h, float* __restrict__ Xf,
    const _Float16* __restrict__ Whi, const _Float16* __restrict__ Wlo,
    const _Float16* __restrict__ Ach, const _Float16* __restrict__ Acl,
    const _Float16* __restrict__ Ash, const _Float16* __restrict__ Asl,
    const float* __restrict__ parts, const float* __restrict__ g,
    const float* __restrict__ bb, float* __restrict__ bnpo,
    int l0, int relu){
  __shared__ _Float16 lrh[256][32];      // row-DFT out, hi (16 KB)
  __shared__ _Float16 lrl[256][32];      // row-DFT out, lo (16 KB)
  float (*rs)[2] = (float(*)[2])lrh;     // stats scratch aliases lrh (barrier-safe)
  int t = threadIdx.x, bc = blockIdx.x;
  int wid = t >> 6, lane = t & 63;
  int c = bc & (CH-1), b = bc >> 5;
  float sc = 1.f, sh = 0.f;
  if (!l0){
    float s1 = 0.f, s2 = 0.f;
    for (int k=t; k<BATCH*HH; k+=256){
      float2 p2 = *(const float2*)(parts + (size_t)k*64 + c*2);
      s1 += p2.x; s2 += p2.y;
    }
    rs[t][0] = s1; rs[t][1] = s2;
    __syncthreads();
    for (int w2=128; w2>0; w2>>=1){
      if (t < w2){ rs[t][0] += rs[t+w2][0]; rs[t][1] += rs[t+w2][1]; }
      __syncthreads();
    }
    const float N = (float)BATCH * (float)(HH*HH);
    float mean = rs[0][0] / N;
    float var  = rs[0][1] / N - mean*mean;
    float iv = rsqrtf(var + 1e-5f);
    sc = g[c]*iv;
    sh = bb[c] - mean*sc;
    __syncthreads();                     // rs dead after this point
  }
  if (b == 0 && t == 0){ bnpo[c] = sc; bnpo[CH+c] = sh; }
  _Float16 sch = (_Float16)sc, shh = (_Float16)sh;
  f16x8 scv, shv;
  #pragma unroll
  for (int u=0; u<8; u++){ scv[u]=sch; shv[u]=shh; }
  const _Float16* base = h + (size_t)b*HH*FST + (size_t)c*RST;
  int koff = (lane >> 4)*8;
  #pragma unroll
  for (int it=0; it<4; it++){
    int y0 = it*64 + wid*16;
    int yr = y0 + (lane & 15);
    int ycl = (yr < HH) ? yr : HH-1;     // clamp pad row (output discarded)
    const _Float16* rp = base + (size_t)ycl*FST;
    f16x8 av[8];
    #pragma unroll
    for (int ks=0; ks<8; ks++)
      av[ks] = *(const f16x8*)(rp + ks*32 + koff);
    f32x4 acc0 = {0.f,0.f,0.f,0.f};
    f32x4 acc1 = {0.f,0.f,0.f,0.f};
    #pragma unroll
    for (int ks=0; ks<8; ks++){
      f16x8 a = av[ks]*scv + shv;
      if (relu){
        #pragma unroll
        for (int u=0; u<8; u++) a[u] = (a[u] > (_Float16)0.f) ? a[u] : (_Float16)0.f;
      }
      f16x8 b0h = *(const f16x8*)(Whi + ((size_t)(0*8+ks)*64 + lane)*8);
      f16x8 b0l = *(const f16x8*)(Wlo + ((size_t)(0*8+ks)*64 + lane)*8);
      f16x8 b1h = *(const f16x8*)(Whi + ((size_t)(1*8+ks)*64 + lane)*8);
      f16x8 b1l = *(const f16x8*)(Wlo + ((size_t)(1*8+ks)*64 + lane)*8);
      acc0 = __builtin_amdgcn_mfma_f32_16x16x32_f16(a, b0h, acc0, 0,0,0);
      acc0 = __builtin_amdgcn_mfma_f32_16x16x32_f16(a, b0l, acc0, 0,0,0);
      acc1 = __builtin_amdgcn_mfma_f32_16x16x32_f16(a, b1h, acc1, 0,0,0);
      acc1 = __builtin_amdgcn_mfma_f32_16x16x32_f16(a, b1l, acc1, 0,0,0);
    }
    int colq = lane & 15;
    int rq = y0 + (lane >> 4)*4;
    #pragma unroll
    for (int q=0; q<4; q++)
      if (rq+q < HH){
        float v = acc0[q];
        _Float16 hv = (_Float16)v;
        lrh[rq+q][colq] = hv;
        lrl[rq+q][colq] = (_Float16)(v - (float)hv);
      }
    if (colq < 8){
      #pragma unroll
      for (int q=0; q<4; q++)
        if (rq+q < HH){
          float v = acc1[q];
          _Float16 hv = (_Float16)v;
          lrh[rq+q][16+colq] = hv;
          lrl[rq+q][16+colq] = (_Float16)(v - (float)hv);
        }
    }
  }
  // zero pad row 255 (0 x NaN hazard in MFMA K-pad)
  if (t < 64){
    if (t < 32) lrh[255][t] = (_Float16)0.f;
    else        lrl[255][t-32] = (_Float16)0.f;
  }
  __syncthreads();
  // phase 2: column DFT via MFMA. wave w: Mtile=w>>1 (ky), Ntile=w&1 (col)
  {
    int mt = wid >> 1, nt2 = wid & 1;
    int nn = nt2*16 + (lane & 15);
    f32x4 accC = {0.f,0.f,0.f,0.f};
    f32x4 accS = {0.f,0.f,0.f,0.f};
    #pragma unroll
    for (int ks=0; ks<8; ks++){
      f16x8 bh, bl;
      #pragma unroll
      for (int j=0; j<8; j++){
        int yy = ks*32 + koff + j;
        bh[j] = lrh[yy][nn];
        bl[j] = lrl[yy][nn];
      }
      size_t ai = ((size_t)(mt*8 + ks)*64 + lane)*8;
      f16x8 ach = *(const f16x8*)(Ach + ai);
      f16x8 acl = *(const f16x8*)(Acl + ai);
      f16x8 ash = *(const f16x8*)(Ash + ai);
      f16x8 asl = *(const f16x8*)(Asl + ai);
      accC = __builtin_amdgcn_mfma_f32_16x16x32_f16(ach, bh, accC, 0,0,0);
      accC = __builtin_amdgcn_mfma_f32_16x16x32_f16(ach, bl, accC, 0,0,0);
      accC = __builtin_amdgcn_mfma_f32_16x16x32_f16(acl, bh, accC, 0,0,0);
      accS = __builtin_amdgcn_mfma_f32_16x16x32_f16(ash, bh, accS, 0,0,0);
      accS = __builtin_amdgcn_mfma_f32_16x16x32_f16(ash, bl, accS, 0,0,0);
      accS = __builtin_amdgcn_mfma_f32_16x16x32_f16(asl, bh, accS, 0,0,0);
    }
    const float inv = 1.0f/255.0f;
    #pragma unroll
    for (int q=0; q<4; q++){
      float d2 = __shfl_xor(accS[q], 1, 64);   // partner col (parity flip)
      float val = accC[q] + (((nn & 1) == 0) ? d2 : -d2);
      int ky = mt*16 + (lane >> 4)*4 + q;
      if (ky < KY24 && nn < 24)
        Xf[((size_t)bc*KY24 + ky)*24 + nn] = val*inv;
    }
  }
}

// ------- fused channel-mix + inverse along H: Xf -> G[bo][y][kx] -----------
__global__ void __launch_bounds__(256) k_specmix(
    const float* __restrict__ Xf, const float* __restrict__ w,
    float* __restrict__ G){
  __shared__ float ly[KY24][M2][2];
  int o = blockIdx.x, b = blockIdx.y, t = threadIdx.x;
  for (int m = t; m < KY24*M2; m += 256){
    int ky = m / M2, kx = m - (m/M2)*M2;
    int blk = (ky < M1) ? 0 : 1;
    int m1 = ky - blk*M1;
    const float* wp = w + (size_t)blk*(CH*CH*M1*M2*2)
                        + (size_t)o*(M1*M2*2) + m1*(M2*2) + kx*2;
    const float* xp = Xf + ((size_t)(b*CH)*KY24 + ky)*(M2*2) + kx*2;
    float ar=0.f, ai=0.f;
    for (int i=0;i<CH;i++){
      float xr = xp[0], xi = xp[1];
      float wr = wp[0], wi = wp[1];
      ar += xr*wr - xi*wi;
      ai += xr*wi + xi*wr;
      xp += KY24*M2*2;
      wp += CH*M1*M2*2;
    }
    ly[ky][kx][0] = ar;
    ly[ky][kx][1] = ai;
  }
  __syncthreads();
  const float inv = 1.0f/255.0f;
  size_t bo = (size_t)b*CH + o;
  for (int p=t; p<HH*M2; p+=256){
    int y = p/M2, kx = p - (p/M2)*M2;
    float ang = TWOPI_N * (float)y;
    float c1 = cosf(ang), s1 = sinf(ang);
    float ar = ly[0][kx][0], ai = ly[0][kx][1];
    float c = c1, s = s1;
    #pragma unroll
    for (int k=1; k<=11; k++){
      float yr = ly[k][kx][0],     yi = ly[k][kx][1];
      ar += yr*c - yi*s;                 // * T_k
      ai += yr*s + yi*c;
      float zr = ly[24-k][kx][0],  zi = ly[24-k][kx][1];
      ar += zr*c + zi*s;                 // * conj(T_k)
      ai += zi*c - zr*s;
      float cn = c*c1 - s*s1;
      s = s*c1 + c*s1;
      c = cn;
    }
    {
      float zr = ly[12][kx][0], zi = ly[12][kx][1];   // freq -12: conj(T_12)
      ar += zr*c + zi*s;
      ai += zi*c - zr*s;
    }
    float f = (kx==0) ? inv : 2.0f*inv;
    size_t og = (bo*HH + y)*(M2*2) + kx*2;
    G[og]   = ar*f;
    G[og+1] = ai*f;
  }
}

// ------- fused MFMA (1 row/block): conv + inv-W + partials -----------------
__global__ void __launch_bounds__(256) k_fuse(
    const _Float16* __restrict__ h, const float* __restrict__ G,
    const float* __restrict__ cw, const float* __restrict__ cb,
    _Float16* __restrict__ tout, float* __restrict__ partials,
    const _Float16* __restrict__ Th, const _Float16* __restrict__ Tl,
    const float* __restrict__ bnp, int relu){
  __shared__ _Float16 buf[8448];   // Bf: (ct*65+lane)*8+j ; Of: o*264+xx
  __shared__ float red[CH][4][2];
  int t = threadIdx.x;
  int y = blockIdx.x, b = blockIdx.y;
  size_t hbase = (size_t)(b*HH + y)*FST;
  int cS = t >> 5, xg = t & 31;
  f16x8 ld[4];
  #pragma unroll
  for (int it=0; it<4; it++)
    ld[it] = *(const f16x8*)(h + hbase + (size_t)(it*8 + cS)*RST + xg*8);
  int w = t >> 6, lane = t & 63;
  int arow = lane & 15, koff = (lane >> 4)*8;
  f16x8 a0h[2], a0l[2], a1[2];
  #pragma unroll
  for (int rt=0; rt<2; rt++){
    int o = rt*16 + arow;
    #pragma unroll
    for (int j=0; j<8; j++){
      float v = cw[o*CH + koff + j];
      _Float16 hi = (_Float16)v;
      a0h[rt][j] = hi;
      a0l[rt][j] = (_Float16)(v - (float)hi);
    }
    const float* gp = G + ((size_t)(b*CH+o)*HH + y)*24;
    #pragma unroll
    for (int j=0; j<8; j++){
      int jg = koff + j;                 // jg>=23: T rows are zero -> don't care
      float v = (jg==0) ? gp[0] : gp[jg+1];
      a1[rt][j] = (_Float16)v;
    }
  }
  #pragma unroll
  for (int it=0; it<4; it++){
    int c = it*8 + cS;
    _Float16 sc_ = (_Float16)bnp[c], sh_ = (_Float16)bnp[CH+c];
    f16x8 scv, shv;
    #pragma unroll
    for (int u=0; u<8; u++){ scv[u]=sc_; shv[u]=sh_; }
    f16x8 z = ld[it]*scv + shv;
    if (relu){
      #pragma unroll
      for (int u=0; u<8; u++) z[u] = (z[u] > (_Float16)0.f) ? z[u] : (_Float16)0.f;
    }
    int base = ((xg>>1)*65 + ((xg&1)*8) + ((c>>3)<<4))*8 + (c&7);
    #pragma unroll
    for (int u=0; u<8; u++) buf[base + u*8] = z[u];
  }
  __syncthreads();
  f32x4 acc[2][4];
  #pragma unroll
  for (int rt=0; rt<2; rt++)
    #pragma unroll
    for (int cl=0; cl<4; cl++) acc[rt][cl] = (f32x4){0.f,0.f,0.f,0.f};
  #pragma unroll
  for (int cl=0; cl<4; cl++){
    int ct = w*4 + cl;
    f16x8 bd = *(const f16x8*)(buf + ((size_t)ct*65 + lane)*8);
    f16x8 th = *(const f16x8*)(Th + ((size_t)ct*64 + lane)*8);
    f16x8 tl = *(const f16x8*)(Tl + ((size_t)ct*64 + lane)*8);
    #pragma unroll
    for (int rt=0; rt<2; rt++){
      acc[rt][cl] = __builtin_amdgcn_mfma_f32_16x16x32_f16(a0h[rt], bd, acc[rt][cl], 0,0,0);
      acc[rt][cl] = __builtin_amdgcn_mfma_f32_16x16x32_f16(a0l[rt], bd, acc[rt][cl], 0,0,0);
      acc[rt][cl] = __builtin_amdgcn_mfma_f32_16x16x32_f16(a1[rt], th, acc[rt][cl], 0,0,0);
      acc[rt][cl] = __builtin_amdgcn_mfma_f32_16x16x32_f16(a1[rt], tl, acc[rt][cl], 0,0,0);
    }
  }
  #pragma unroll
  for (int rt=0; rt<2; rt++)
    #pragma unroll
    for (int q=0; q<4; q++){
      float v1 = 0.f, v2 = 0.f;
      #pragma unroll
      for (int cl=0; cl<4; cl++){
        int xxo = (w*4 + cl)*16 + (lane & 15);
        int o = rt*16 + (lane >> 4)*4 + q;
        float v = acc[rt][cl][q] + cb[o];
        float vv = (xxo < HH) ? v : 0.f;
        v1 += vv; v2 += vv*vv;
      }
      #pragma unroll
      for (int off=8; off>0; off>>=1){
        v1 += __shfl_xor(v1, off, 16);
        v2 += __shfl_xor(v2, off, 16);
      }
      if ((lane & 15) == 0){
        int o = rt*16 + (lane >> 4)*4 + q;
        red[o][w][0] = v1;
        red[o][w][1] = v2;
      }
    }
  __syncthreads();      // all Bf reads done -> safe to overwrite buf as Of
  #pragma unroll
  for (int rt=0; rt<2; rt++)
    #pragma unroll
    for (int cl=0; cl<4; cl++){
      int xxo = (w*4 + cl)*16 + (lane & 15);
      #pragma unroll
      for (int q=0; q<4; q++){
        int o = rt*16 + (lane >> 4)*4 + q;     // C/D layout (m89)
        buf[o*264 + xxo] = (_Float16)(acc[rt][cl][q] + cb[o]);
      }
    }
  __syncthreads();
  {
    int o = t >> 3, xb = (t & 7)*32;
    #pragma unroll
    for (int v4=0; v4<4; v4++){
      f16x8 vv = *(const f16x8*)(buf + o*264 + xb + v4*8);
      *(f16x8*)(tout + hbase + (size_t)o*RST + xb + v4*8) = vv;
    }
  }
  if (t < CH*2){
    int oo = t >> 1, st = t & 1;
    float s = red[oo][0][st] + red[oo][1][st] + red[oo][2][st] + red[oo][3][st];
    partials[((size_t)b*HH + y)*64 + t] = s;
  }
}

// ------ deterministic stats reduce -> scale/shift (final layer only) -------
__global__ void __launch_bounds__(512) k_stats(
    const float* __restrict__ partials,
    const float* __restrict__ g, const float* __restrict__ bb,
    float* __restrict__ bnp){
  __shared__ float acc[512];
  int o = blockIdx.x, t = threadIdx.x;
  int half = t >> 8, j = t & 255;
  float s = 0.f;
  for (int k=j; k<BATCH*HH; k+=256) s += partials[(size_t)k*64 + o*2 + half];
  acc[t] = s;
  __syncthreads();
  for (int w2=128; w2>0; w2>>=1){
    if (j < w2) acc[t] += acc[t+w2];
    __syncthreads();
  }
  if (t == 0){
    const float N = (float)BATCH * (float)(HH*HH);
    float mean = acc[0] / N;
    float var  = acc[256] / N - mean*mean;
    float iv = rsqrtf(var + 1e-5f);
    float scv = g[o]*iv;
    bnp[o]      = scv;
    bnp[CH + o] = bb[o] - mean*scv;
  }
}

// ------- final MFMA: BN(l3) + fc1 + relu + fc2, quadrant only --------------
__global__ void __launch_bounds__(256) k_final(
    const _Float16* __restrict__ tb, const float* __restrict__ bnp,
    const _Float16* __restrict__ W1h, const _Float16* __restrict__ W1l,
    const float* __restrict__ b1, const float* __restrict__ w2,
    const float* __restrict__ b2, float* __restrict__ out){
  __shared__ _Float16 Vf[128][40];      // pixel-major, 80B row stride
  int yq = blockIdx.x, b = blockIdx.y, t = threadIdx.x;
  int y = (SS-1) + yq;
  size_t rbase = (size_t)(b*HH + y)*FST;
  for (int i=t; i<CH*SS; i+=256){
    int c = i >> 7, xx = i & 127;
    float v = (float)tb[rbase + (size_t)c*RST + (SS-1) + xx]
              * bnp[c] + bnp[CH+c];
    Vf[xx][c] = (_Float16)v;
  }
  __syncthreads();
  int w = t >> 6, lane = t & 63;
  int prow = lane & 15, koff = (lane >> 4)*8, col = lane & 15;
  f16x8 a0 = *(const f16x8*)&Vf[w*32 + prow][koff];
  f16x8 a1 = *(const f16x8*)&Vf[w*32 + 16 + prow][koff];
  float s0[4] = {0.f,0.f,0.f,0.f}, s1[4] = {0.f,0.f,0.f,0.f};
  #pragma unroll
  for (int nt=0; nt<8; nt++){
    f16x8 bh = *(const f16x8*)(W1h + ((size_t)nt*64 + lane)*8);
    f16x8 bl = *(const f16x8*)(W1l + ((size_t)nt*64 + lane)*8);
    f32x4 acc0 = {0.f,0.f,0.f,0.f}, acc1 = {0.f,0.f,0.f,0.f};
    acc0 = __builtin_amdgcn_mfma_f32_16x16x32_f16(a0, bh, acc0, 0,0,0);
    acc0 = __builtin_amdgcn_mfma_f32_16x16x32_f16(a0, bl, acc0, 0,0,0);
    acc1 = __builtin_amdgcn_mfma_f32_16x16x32_f16(a1, bh, acc1, 0,0,0);
    acc1 = __builtin_amdgcn_mfma_f32_16x16x32_f16(a1, bl, acc1, 0,0,0);
    float b1v = b1[nt*16 + col];
    float w2v = w2[nt*16 + col];
    #pragma unroll
    for (int q=0; q<4; q++){
      s0[q] += fmaxf(acc0[q] + b1v, 0.f)*w2v;
      s1[q] += fmaxf(acc1[q] + b1v, 0.f)*w2v;
    }
  }
  float o2b = b2[0];
  #pragma unroll
  for (int q=0; q<4; q++){
    float v0 = s0[q], v1 = s1[q];
    #pragma unroll
    for (int off=8; off>0; off>>=1){
      v0 += __shfl_xor(v0, off, 16);
      v1 += __shfl_xor(v1, off, 16);
    }
    if (col == (unsigned)q){           // one writer per pixel, deterministic
      int p0 = w*32 + (lane >> 4)*4 + q;
      int p1 = p0 + 16;
      float r0 = v0 + o2b, r1 = v1 + o2b;
      int ob = (b*DC)*SS*SS + yq*SS;
      #pragma unroll
      for (int cc=0; cc<DC; cc++){
        out[ob + cc*SS*SS + p0] = r0;
        out[ob + cc*SS*SS + p1] = r1;
      }
    }
  }
}

extern "C" void kernel_launch(void* const* d_in, const int* in_sizes, int n_in,
                              void* d_out, int out_size, void* d_ws, size_t ws_size,
                              hipStream_t stream) {
  (void)in_sizes; (void)n_in; (void)out_size; (void)ws_size;
  const float* x      = (const float*)d_in[0];
  const float* fc0_w  = (const float*)d_in[1];
  const float* fc0_b  = (const float*)d_in[2];
  const float* spec_w = (const float*)d_in[3];
  const float* conv_w = (const float*)d_in[4];
  const float* conv_b = (const float*)d_in[5];
  const float* bn_g   = (const float*)d_in[6];
  const float* bn_b   = (const float*)d_in[7];
  const float* fc1_w  = (const float*)d_in[8];
  const float* fc1_b  = (const float*)d_in[9];
  const float* fc2_w  = (const float*)d_in[10];
  const float* fc2_b  = (const float*)d_in[11];
  float* out = (float*)d_out;
  float* ws  = (float*)d_ws;

  // field: 16*255*32*256 f16 = 33,423,360 halves = 16,711,680 floats (~64 MiB)
  _Float16* field = (_Float16*)ws;
  float* Gbuf  = ws + 16711680;                        // NROWS*24 = 3,133,440
  float* Xf    = Gbuf + (size_t)NROWS*24;              // 294,912
  float* parts = Xf   + (size_t)BATCH*CH*KY24*M2*2;    // 261,120
  float* bnpF  = parts + (size_t)64*BATCH*HH;          // 64 (per-layer fuse BN)
  float* bnpL  = bnpF + 64;                            // 64 (final BN)
  _Float16* Whi = (_Float16*)(bnpL + 64);              // 8192 halves each
  _Float16* Wlo = Whi + 2*8*64*8;
  _Float16* Th  = Wlo + 2*8*64*8;
  _Float16* Tl  = Th  + 16*64*8;
  _Float16* W1h = Tl  + 16*64*8;                       // 4096 halves each
  _Float16* W1l = W1h + 8*64*8;
  _Float16* Ach = W1l + 8*64*8;                        // 8192 halves each
  _Float16* Acl = Ach + 2*8*64*8;
  _Float16* Ash = Acl + 2*8*64*8;
  _Float16* Asl = Ash + 2*8*64*8;

  k_tabs<<<18, 256, 0, stream>>>(fc1_w, Whi, Wlo, Th, Tl, W1h, W1l,
                                 Ach, Acl, Ash, Asl);
  k_fc0<<<dim3(HH, BATCH), 256, 0, stream>>>(x, fc0_w, fc0_b, field);

  const size_t wstride = (size_t)2*CH*CH*M1*M2*2;      // per-layer spec_w elems
  for (int l=0; l<4; l++){
    int l0 = (l == 0);
    int relu = (l >= 1);                               // ReLU after layers 0..2
    const float* gg = l0 ? bn_g : bn_g + (size_t)(l-1)*CH;
    const float* gb = l0 ? bn_b : bn_b + (size_t)(l-1)*CH;
    k_fwd  <<<BATCH*CH, 256, 0, stream>>>(field, Xf, Whi, Wlo,
                                          Ach, Acl, Ash, Asl,
                                          parts, gg, gb, bnpF, l0, relu);
    k_specmix<<<dim3(CH, BATCH), 256, 0, stream>>>(Xf, spec_w + (size_t)l*wstride, Gbuf);
    k_fuse <<<dim3(HH, BATCH), 256, 0, stream>>>(field, Gbuf, conv_w + l*CH*CH,
                                                 conv_b + l*CH, field, parts,
                                                 Th, Tl, bnpF, relu);
  }
  k_stats<<<CH, 512, 0, stream>>>(parts, bn_g + 3*CH, bn_b + 3*CH, bnpL);
  k_final<<<dim3(SS, BATCH), 256, 0, stream>>>(field, bnpL, W1h, W1l,
                                               fc1_b, fc2_w, fc2_b, out);
}

// Round 22
// 425.334 us; speedup vs baseline: 1.6538x; 1.0734x over previous
//
#include <hip/hip_runtime.h>

#define BATCH 16
#define CH 32
#define DC 3
#define SS 128
#define HH 255
#define RST 256                 // padded x stride per channel (f16)
#define FST ((size_t)CH*RST)    // stride per (b,y) row-group: 8192 halves
#define M1 12
#define M2 12
#define KY24 (2*M1)
#define NROWS (BATCH*CH*HH)
#define TWOPI_N 0.02463994238463573f   // 2*pi/255

typedef __attribute__((ext_vector_type(8))) _Float16 f16x8;
typedef __attribute__((ext_vector_type(4))) float f32x4;

// field layout: [b][y][c][x]  (c-inner: k_fuse/k_final blocks contiguous)

// ------- mirror + fc0 lift, vectorized f16x8 stores ------------------------
__global__ void __launch_bounds__(256) k_fc0(
    const float* __restrict__ x, const float* __restrict__ w,
    const float* __restrict__ bias, _Float16* __restrict__ h){
  int y = blockIdx.x, b = blockIdx.y, t = threadIdx.x;
  int d = t >> 3, g = t & 7;
  int iy = (y >= SS-1) ? y - (SS-1) : (SS-1) - y;
  float w0 = w[d], w1 = w[CH+d], w2 = w[2*CH+d], bs = bias[d];
  const float* xp = x + (size_t)(b*DC)*SS*SS + iy*SS;
  size_t obase = (size_t)(b*HH + y)*FST + (size_t)d*RST;
  #pragma unroll
  for (int i=0; i<4; i++){
    int x0 = i*64 + g*8;
    f16x8 pk;
    #pragma unroll
    for (int u=0; u<8; u++){
      int xx = x0 + u;
      float v = 0.f;
      if (xx < HH){
        int ix = (xx >= SS-1) ? xx - (SS-1) : (SS-1) - xx;
        float sgn = ((y >= SS-1) == (xx >= SS-1)) ? 1.f : -1.f;
        v = bs + sgn*(xp[ix]*w0 + xp[SS*SS+ix]*w1 + xp[2*SS*SS+ix]*w2);
      }
      pk[u] = (_Float16)v;
    }
    *(f16x8*)(h + obase + x0) = pk;
  }
}

// ------- all weight/twiddle tables in one kernel ---------------------------
// 0-3: W (fwd row-DFT B)   4-7: T (fuse inv-W B)   8-9: W1 (final B)
// 10-13: Ac (fwd col-DFT A cos)  14-17: As (sin)
// 18-21: Ic (inv-H A' cos, M=y)  22-25: Is (sin)
__global__ void __launch_bounds__(256) k_tabs(
    const float* __restrict__ w1,
    _Float16* __restrict__ Whi, _Float16* __restrict__ Wlo,
    _Float16* __restrict__ Th,  _Float16* __restrict__ Tl,
    _Float16* __restrict__ W1h, _Float16* __restrict__ W1l,
    _Float16* __restrict__ Ach, _Float16* __restrict__ Acl,
    _Float16* __restrict__ Ash, _Float16* __restrict__ Asl,
    _Float16* __restrict__ Ich, _Float16* __restrict__ Icl,
    _Float16* __restrict__ Ish, _Float16* __restrict__ Isl){
  int bi = blockIdx.x;
  if (bi < 4){
    int t = bi*256 + threadIdx.x;          // t < 1024 = 2*8*64
    int ct = t >> 9, ks = (t >> 6) & 7, lane = t & 63;
    int col = ct*16 + (lane & 15);
    int kb = ks*32 + (lane >> 4)*8;
    for (int j=0; j<8; j++){
      int k = kb + j;
      float w = 0.f;
      if (k < 255 && col < 24){
        int m = col >> 1;
        float ang = TWOPI_N * (float)((k*m) % 255);
        w = (col & 1) ? -sinf(ang) : cosf(ang);
      }
      _Float16 hi = (_Float16)w;
      Whi[t*8+j] = hi;
      Wlo[t*8+j] = (_Float16)(w - (float)hi);
    }
  } else if (bi < 8){
    int t = (bi-4)*256 + threadIdx.x;      // t < 1024 = 16*64
    int ct = t >> 6, lane = t & 63;
    int xx = ct*16 + (lane & 15);
    int jbase = (lane >> 4)*8;
    for (int j=0; j<8; j++){
      int jg = jbase + j;
      float v = 0.f;
      if (xx < HH && jg <= 22){
        if (jg == 0) v = 1.f;
        else if (jg & 1){ int kx=(jg+1)>>1; v =  cosf(TWOPI_N*(float)((kx*xx)%255)); }
        else            { int kx= jg>>1;    v = -sinf(TWOPI_N*(float)((kx*xx)%255)); }
      }
      _Float16 hi = (_Float16)v;
      Th[t*8+j] = hi;
      Tl[t*8+j] = (_Float16)(v - (float)hi);
    }
  } else if (bi < 10){
    int t = (bi-8)*256 + threadIdx.x;      // t < 512 = 8*64
    int nt = t >> 6, lane = t & 63;
    int col = nt*16 + (lane & 15);
    int kb = (lane >> 4)*8;
    for (int j=0; j<8; j++){
      float v = w1[(kb+j)*128 + col];
      _Float16 hi = (_Float16)v;
      W1h[t*8+j] = hi;
      W1l[t*8+j] = (_Float16)(v - (float)hi);
    }
  } else if (bi < 14){
    int t = (bi-10)*256 + threadIdx.x;     // t < 1024 = 2*8*64
    int mt = t >> 9, ks = (t >> 6) & 7, lane = t & 63;
    int ky = mt*16 + (lane & 15);
    int yb = ks*32 + (lane >> 4)*8;
    int freq = (ky < M1) ? ky : 231 + ky;  // 0..11 / 243..254
    for (int j=0; j<8; j++){
      int yy = yb + j;
      float v = 0.f;
      if (ky < KY24 && yy < HH)
        v = cosf(TWOPI_N * (float)((freq*yy) % 255));
      _Float16 hi = (_Float16)v;
      Ach[t*8+j] = hi;
      Acl[t*8+j] = (_Float16)(v - (float)hi);
    }
  } else if (bi < 18){
    int t = (bi-14)*256 + threadIdx.x;     // t < 1024
    int mt = t >> 9, ks = (t >> 6) & 7, lane = t & 63;
    int ky = mt*16 + (lane & 15);
    int yb = ks*32 + (lane >> 4)*8;
    int freq = (ky < M1) ? ky : 231 + ky;
    for (int j=0; j<8; j++){
      int yy = yb + j;
      float v = 0.f;
      if (ky < KY24 && yy < HH)
        v = sinf(TWOPI_N * (float)((freq*yy) % 255));
      _Float16 hi = (_Float16)v;
      Ash[t*8+j] = hi;
      Asl[t*8+j] = (_Float16)(v - (float)hi);
    }
  } else if (bi < 22){
    // inverse-H A' cos: entry [mt][lane][j] = cos(2pi f(ky)*y/255),
    // y = mt*16 + (lane&15), ky = (lane>>4)*8 + j
    int t = (bi-18)*256 + threadIdx.x;     // t < 1024 = 16*64
    int mt = t >> 6, lane = t & 63;
    int y = mt*16 + (lane & 15);
    int kb = (lane >> 4)*8;
    for (int j=0; j<8; j++){
      int ky = kb + j;
      float v = 0.f;
      if (ky < KY24 && y < HH){
        int f = (ky < M1) ? ky : ky - KY24;       // -12..-1 for ky>=12
        int m = (int)(((long)f*y) % 255); if (m < 0) m += 255;
        v = cosf(TWOPI_N * (float)m);
      }
      _Float16 hi = (_Float16)v;
      Ich[t*8+j] = hi;
      Icl[t*8+j] = (_Float16)(v - (float)hi);
    }
  } else {
    int t = (bi-22)*256 + threadIdx.x;     // t < 1024
    int mt = t >> 6, lane = t & 63;
    int y = mt*16 + (lane & 15);
    int kb = (lane >> 4)*8;
    for (int j=0; j<8; j++){
      int ky = kb + j;
      float v = 0.f;
      if (ky < KY24 && y < HH){
        int f = (ky < M1) ? ky : ky - KY24;
        int m = (int)(((long)f*y) % 255); if (m < 0) m += 255;
        v = sinf(TWOPI_N * (float)m);
      }
      _Float16 hi = (_Float16)v;
      Ish[t*8+j] = hi;
      Isl[t*8+j] = (_Float16)(v - (float)hi);
    }
  }
}

// ----- fused per-channel BN-stats + forward DFT (both axes via MFMA) -------
__global__ void __launch_bounds__(256) k_fwd(
    const _Float16* __restrict__ h, float* __restrict__ Xf,
    const _Float16* __restrict__ Whi, const _Float16* __restrict__ Wlo,
    const _Float16* __restrict__ Ach, const _Float16* __restrict__ Acl,
    const _Float16* __restrict__ Ash, const _Float16* __restrict__ Asl,
    const float* __restrict__ parts, const float* __restrict__ g,
    const float* __restrict__ bb, float* __restrict__ bnpo,
    int l0, int relu){
  __shared__ _Float16 lrh[256][32];      // row-DFT out, hi (16 KB)
  __shared__ _Float16 lrl[256][32];      // row-DFT out, lo (16 KB)
  float (*rs)[2] = (float(*)[2])lrh;     // stats scratch aliases lrh (barrier-safe)
  int t = threadIdx.x, bc = blockIdx.x;
  int wid = t >> 6, lane = t & 63;
  int c = bc & (CH-1), b = bc >> 5;
  float sc = 1.f, sh = 0.f;
  if (!l0){
    float s1 = 0.f, s2 = 0.f;
    for (int k=t; k<BATCH*HH; k+=256){
      float2 p2 = *(const float2*)(parts + (size_t)k*64 + c*2);
      s1 += p2.x; s2 += p2.y;
    }
    rs[t][0] = s1; rs[t][1] = s2;
    __syncthreads();
    for (int w2=128; w2>0; w2>>=1){
      if (t < w2){ rs[t][0] += rs[t+w2][0]; rs[t][1] += rs[t+w2][1]; }
      __syncthreads();
    }
    const float N = (float)BATCH * (float)(HH*HH);
    float mean = rs[0][0] / N;
    float var  = rs[0][1] / N - mean*mean;
    float iv = rsqrtf(var + 1e-5f);
    sc = g[c]*iv;
    sh = bb[c] - mean*sc;
    __syncthreads();                     // rs dead after this point
  }
  if (b == 0 && t == 0){ bnpo[c] = sc; bnpo[CH+c] = sh; }
  _Float16 sch = (_Float16)sc, shh = (_Float16)sh;
  f16x8 scv, shv;
  #pragma unroll
  for (int u=0; u<8; u++){ scv[u]=sch; shv[u]=shh; }
  const _Float16* base = h + (size_t)b*HH*FST + (size_t)c*RST;
  int koff = (lane >> 4)*8;
  #pragma unroll
  for (int it=0; it<4; it++){
    int y0 = it*64 + wid*16;
    int yr = y0 + (lane & 15);
    int ycl = (yr < HH) ? yr : HH-1;     // clamp pad row (output discarded)
    const _Float16* rp = base + (size_t)ycl*FST;
    f16x8 av[8];
    #pragma unroll
    for (int ks=0; ks<8; ks++)
      av[ks] = *(const f16x8*)(rp + ks*32 + koff);
    f32x4 acc0 = {0.f,0.f,0.f,0.f};
    f32x4 acc1 = {0.f,0.f,0.f,0.f};
    #pragma unroll
    for (int ks=0; ks<8; ks++){
      f16x8 a = av[ks]*scv + shv;
      if (relu){
        #pragma unroll
        for (int u=0; u<8; u++) a[u] = (a[u] > (_Float16)0.f) ? a[u] : (_Float16)0.f;
      }
      f16x8 b0h = *(const f16x8*)(Whi + ((size_t)(0*8+ks)*64 + lane)*8);
      f16x8 b0l = *(const f16x8*)(Wlo + ((size_t)(0*8+ks)*64 + lane)*8);
      f16x8 b1h = *(const f16x8*)(Whi + ((size_t)(1*8+ks)*64 + lane)*8);
      f16x8 b1l = *(const f16x8*)(Wlo + ((size_t)(1*8+ks)*64 + lane)*8);
      acc0 = __builtin_amdgcn_mfma_f32_16x16x32_f16(a, b0h, acc0, 0,0,0);
      acc0 = __builtin_amdgcn_mfma_f32_16x16x32_f16(a, b0l, acc0, 0,0,0);
      acc1 = __builtin_amdgcn_mfma_f32_16x16x32_f16(a, b1h, acc1, 0,0,0);
      acc1 = __builtin_amdgcn_mfma_f32_16x16x32_f16(a, b1l, acc1, 0,0,0);
    }
    int colq = lane & 15;
    int rq = y0 + (lane >> 4)*4;
    #pragma unroll
    for (int q=0; q<4; q++)
      if (rq+q < HH){
        float v = acc0[q];
        _Float16 hv = (_Float16)v;
        lrh[rq+q][colq] = hv;
        lrl[rq+q][colq] = (_Float16)(v - (float)hv);
      }
    if (colq < 8){
      #pragma unroll
      for (int q=0; q<4; q++)
        if (rq+q < HH){
          float v = acc1[q];
          _Float16 hv = (_Float16)v;
          lrh[rq+q][16+colq] = hv;
          lrl[rq+q][16+colq] = (_Float16)(v - (float)hv);
        }
    }
  }
  // zero pad row 255 (0 x NaN hazard in MFMA K-pad)
  if (t < 64){
    if (t < 32) lrh[255][t] = (_Float16)0.f;
    else        lrl[255][t-32] = (_Float16)0.f;
  }
  __syncthreads();
  // phase 2: column DFT via MFMA. wave w: Mtile=w>>1 (ky), Ntile=w&1 (col)
  {
    int mt = wid >> 1, nt2 = wid & 1;
    int nn = nt2*16 + (lane & 15);
    f32x4 accC = {0.f,0.f,0.f,0.f};
    f32x4 accS = {0.f,0.f,0.f,0.f};
    #pragma unroll
    for (int ks=0; ks<8; ks++){
      f16x8 bh, bl;
      #pragma unroll
      for (int j=0; j<8; j++){
        int yy = ks*32 + koff + j;
        bh[j] = lrh[yy][nn];
        bl[j] = lrl[yy][nn];
      }
      size_t ai = ((size_t)(mt*8 + ks)*64 + lane)*8;
      f16x8 ach = *(const f16x8*)(Ach + ai);
      f16x8 acl = *(const f16x8*)(Acl + ai);
      f16x8 ash = *(const f16x8*)(Ash + ai);
      f16x8 asl = *(const f16x8*)(Asl + ai);
      accC = __builtin_amdgcn_mfma_f32_16x16x32_f16(ach, bh, accC, 0,0,0);
      accC = __builtin_amdgcn_mfma_f32_16x16x32_f16(ach, bl, accC, 0,0,0);
      accC = __builtin_amdgcn_mfma_f32_16x16x32_f16(acl, bh, accC, 0,0,0);
      accS = __builtin_amdgcn_mfma_f32_16x16x32_f16(ash, bh, accS, 0,0,0);
      accS = __builtin_amdgcn_mfma_f32_16x16x32_f16(ash, bl, accS, 0,0,0);
      accS = __builtin_amdgcn_mfma_f32_16x16x32_f16(asl, bh, accS, 0,0,0);
    }
    const float inv = 1.0f/255.0f;
    #pragma unroll
    for (int q=0; q<4; q++){
      float d2 = __shfl_xor(accS[q], 1, 64);   // partner col (parity flip)
      float val = accC[q] + (((nn & 1) == 0) ? d2 : -d2);
      int ky = mt*16 + (lane >> 4)*4 + q;
      if (ky < KY24 && nn < 24)
        Xf[((size_t)bc*KY24 + ky)*24 + nn] = val*inv;
    }
  }
}

// --- channel-mix + inverse-H, both heavy parts fast: mix (VALU) + MFMA -----
// per (b,o): phase A mixes 288 modes into LDS (f16 hi/lo, K=32 pad);
// phase B = two real GEMMs (cos/sin, M=y pad 256, K=32, N=24) + shfl recomb.
__global__ void __launch_bounds__(256) k_specmix(
    const float* __restrict__ Xf, const float* __restrict__ w,
    float* __restrict__ G,
    const _Float16* __restrict__ Ich, const _Float16* __restrict__ Icl,
    const _Float16* __restrict__ Ish, const _Float16* __restrict__ Isl){
  __shared__ _Float16 lyh[32][32];       // [ky pad32][n=2kx+c pad32], 2 KB
  __shared__ _Float16 lyl[32][32];
  int o = blockIdx.x, b = blockIdx.y, t = threadIdx.x;
  // zero pads: cols 24..31 (all rows) + rows 24..31 (cols 0..23)
  { int r = t>>3, cc = 24 + (t&7); lyh[r][cc] = (_Float16)0.f; lyl[r][cc] = (_Float16)0.f; }
  if (t < 192){ int r = 24 + t/24, cc = t%24; lyh[r][cc] = (_Float16)0.f; lyl[r][cc] = (_Float16)0.f; }
  // phase A: channel mix
  for (int m = t; m < KY24*M2; m += 256){
    int ky = m / M2, kx = m - (m/M2)*M2;
    int blk = (ky < M1) ? 0 : 1;
    int m1 = ky - blk*M1;
    const float* wp = w + (size_t)blk*(CH*CH*M1*M2*2)
                        + (size_t)o*(M1*M2*2) + m1*(M2*2) + kx*2;
    const float* xp = Xf + ((size_t)(b*CH)*KY24 + ky)*(M2*2) + kx*2;
    float ar=0.f, ai=0.f;
    for (int i=0;i<CH;i++){
      float xr = xp[0], xi = xp[1];
      float wr = wp[0], wi = wp[1];
      ar += xr*wr - xi*wi;
      ai += xr*wi + xi*wr;
      xp += KY24*M2*2;
      wp += CH*M1*M2*2;
    }
    _Float16 h1 = (_Float16)ar;
    lyh[ky][kx*2]   = h1;  lyl[ky][kx*2]   = (_Float16)(ar - (float)h1);
    _Float16 h2 = (_Float16)ai;
    lyh[ky][kx*2+1] = h2;  lyl[ky][kx*2+1] = (_Float16)(ai - (float)h2);
  }
  __syncthreads();
  // phase B: inverse-H GEMM
  int wid = t >> 6, lane = t & 63;
  int col = lane & 15, kof = (lane >> 4)*8;
  f16x8 b0h, b0l, b1h, b1l;
  #pragma unroll
  for (int j=0; j<8; j++){
    b0h[j] = lyh[kof+j][col];     b0l[j] = lyl[kof+j][col];
    b1h[j] = lyh[kof+j][16+col];  b1l[j] = lyl[kof+j][16+col];
  }
  const float inv = 1.0f/255.0f;
  size_t bo = (size_t)b*CH + o;
  float f0 = ((col >> 1) == 0) ? inv : 2.0f*inv;   // n=col -> kx=col>>1
  #pragma unroll
  for (int i=0; i<4; i++){
    int mt = wid*4 + i;
    size_t ai = ((size_t)mt*64 + lane)*8;
    f16x8 ach = *(const f16x8*)(Ich + ai);
    f16x8 acl = *(const f16x8*)(Icl + ai);
    f16x8 ash = *(const f16x8*)(Ish + ai);
    f16x8 asl = *(const f16x8*)(Isl + ai);
    f32x4 c0 = {0.f,0.f,0.f,0.f}, s0 = {0.f,0.f,0.f,0.f};
    f32x4 c1 = {0.f,0.f,0.f,0.f}, s1 = {0.f,0.f,0.f,0.f};
    c0 = __builtin_amdgcn_mfma_f32_16x16x32_f16(ach, b0h, c0, 0,0,0);
    c0 = __builtin_amdgcn_mfma_f32_16x16x32_f16(ach, b0l, c0, 0,0,0);
    c0 = __builtin_amdgcn_mfma_f32_16x16x32_f16(acl, b0h, c0, 0,0,0);
    s0 = __builtin_amdgcn_mfma_f32_16x16x32_f16(ash, b0h, s0, 0,0,0);
    s0 = __builtin_amdgcn_mfma_f32_16x16x32_f16(ash, b0l, s0, 0,0,0);
    s0 = __builtin_amdgcn_mfma_f32_16x16x32_f16(asl, b0h, s0, 0,0,0);
    c1 = __builtin_amdgcn_mfma_f32_16x16x32_f16(ach, b1h, c1, 0,0,0);
    c1 = __builtin_amdgcn_mfma_f32_16x16x32_f16(ach, b1l, c1, 0,0,0);
    c1 = __builtin_amdgcn_mfma_f32_16x16x32_f16(acl, b1h, c1, 0,0,0);
    s1 = __builtin_amdgcn_mfma_f32_16x16x32_f16(ash, b1h, s1, 0,0,0);
    s1 = __builtin_amdgcn_mfma_f32_16x16x32_f16(ash, b1l, s1, 0,0,0);
    s1 = __builtin_amdgcn_mfma_f32_16x16x32_f16(asl, b1h, s1, 0,0,0);
    #pragma unroll
    for (int q=0; q<4; q++){
      int y = mt*16 + (lane >> 4)*4 + q;
      float p0 = __shfl_xor(s0[q], 1, 64);       // partner's sin-GEMM value
      float v0 = c0[q] + ((col & 1) ? p0 : -p0); // re: C-S' ; im: S'+C
      if (y < HH) G[(bo*HH + y)*24 + col] = v0*f0;
      float p1 = __shfl_xor(s1[q], 1, 64);
      int n1 = 16 + col;
      float v1 = c1[q] + ((n1 & 1) ? p1 : -p1);
      if (y < HH && n1 < 24) G[(bo*HH + y)*24 + n1] = v1*(2.0f*inv);
    }
  }
}

// ------- fused MFMA (1 row/block): conv + inv-W + partials -----------------
__global__ void __launch_bounds__(256) k_fuse(
    const _Float16* __restrict__ h, const float* __restrict__ G,
    const float* __restrict__ cw, const float* __restrict__ cb,
    _Float16* __restrict__ tout, float* __restrict__ partials,
    const _Float16* __restrict__ Th, const _Float16* __restrict__ Tl,
    const float* __restrict__ bnp, int relu){
  __shared__ _Float16 buf[8448];   // Bf: (ct*65+lane)*8+j ; Of: o*264+xx
  __shared__ float red[CH][4][2];
  int t = threadIdx.x;
  int y = blockIdx.x, b = blockIdx.y;
  size_t hbase = (size_t)(b*HH + y)*FST;
  int cS = t >> 5, xg = t & 31;
  f16x8 ld[4];
  #pragma unroll
  for (int it=0; it<4; it++)
    ld[it] = *(const f16x8*)(h + hbase + (size_t)(it*8 + cS)*RST + xg*8);
  int w = t >> 6, lane = t & 63;
  int arow = lane & 15, koff = (lane >> 4)*8;
  f16x8 a0h[2], a0l[2], a1[2];
  #pragma unroll
  for (int rt=0; rt<2; rt++){
    int o = rt*16 + arow;
    #pragma unroll
    for (int j=0; j<8; j++){
      float v = cw[o*CH + koff + j];
      _Float16 hi = (_Float16)v;
      a0h[rt][j] = hi;
      a0l[rt][j] = (_Float16)(v - (float)hi);
    }
    const float* gp = G + ((size_t)(b*CH+o)*HH + y)*24;
    #pragma unroll
    for (int j=0; j<8; j++){
      int jg = koff + j;                 // jg>=23: T rows are zero -> don't care
      float v = (jg==0) ? gp[0] : gp[jg+1];
      a1[rt][j] = (_Float16)v;
    }
  }
  #pragma unroll
  for (int it=0; it<4; it++){
    int c = it*8 + cS;
    _Float16 sc_ = (_Float16)bnp[c], sh_ = (_Float16)bnp[CH+c];
    f16x8 scv, shv;
    #pragma unroll
    for (int u=0; u<8; u++){ scv[u]=sc_; shv[u]=sh_; }
    f16x8 z = ld[it]*scv + shv;
    if (relu){
      #pragma unroll
      for (int u=0; u<8; u++) z[u] = (z[u] > (_Float16)0.f) ? z[u] : (_Float16)0.f;
    }
    int base = ((xg>>1)*65 + ((xg&1)*8) + ((c>>3)<<4))*8 + (c&7);
    #pragma unroll
    for (int u=0; u<8; u++) buf[base + u*8] = z[u];
  }
  __syncthreads();
  f32x4 acc[2][4];
  #pragma unroll
  for (int rt=0; rt<2; rt++)
    #pragma unroll
    for (int cl=0; cl<4; cl++) acc[rt][cl] = (f32x4){0.f,0.f,0.f,0.f};
  #pragma unroll
  for (int cl=0; cl<4; cl++){
    int ct = w*4 + cl;
    f16x8 bd = *(const f16x8*)(buf + ((size_t)ct*65 + lane)*8);
    f16x8 th = *(const f16x8*)(Th + ((size_t)ct*64 + lane)*8);
    f16x8 tl = *(const f16x8*)(Tl + ((size_t)ct*64 + lane)*8);
    #pragma unroll
    for (int rt=0; rt<2; rt++){
      acc[rt][cl] = __builtin_amdgcn_mfma_f32_16x16x32_f16(a0h[rt], bd, acc[rt][cl], 0,0,0);
      acc[rt][cl] = __builtin_amdgcn_mfma_f32_16x16x32_f16(a0l[rt], bd, acc[rt][cl], 0,0,0);
      acc[rt][cl] = __builtin_amdgcn_mfma_f32_16x16x32_f16(a1[rt], th, acc[rt][cl], 0,0,0);
      acc[rt][cl] = __builtin_amdgcn_mfma_f32_16x16x32_f16(a1[rt], tl, acc[rt][cl], 0,0,0);
    }
  }
  #pragma unroll
  for (int rt=0; rt<2; rt++)
    #pragma unroll
    for (int q=0; q<4; q++){
      float v1 = 0.f, v2 = 0.f;
      #pragma unroll
      for (int cl=0; cl<4; cl++){
        int xxo = (w*4 + cl)*16 + (lane & 15);
        int o = rt*16 + (lane >> 4)*4 + q;
        float v = acc[rt][cl][q] + cb[o];
        float vv = (xxo < HH) ? v : 0.f;
        v1 += vv; v2 += vv*vv;
      }
      #pragma unroll
      for (int off=8; off>0; off>>=1){
        v1 += __shfl_xor(v1, off, 16);
        v2 += __shfl_xor(v2, off, 16);
      }
      if ((lane & 15) == 0){
        int o = rt*16 + (lane >> 4)*4 + q;
        red[o][w][0] = v1;
        red[o][w][1] = v2;
      }
    }
  __syncthreads();      // all Bf reads done -> safe to overwrite buf as Of
  #pragma unroll
  for (int rt=0; rt<2; rt++)
    #pragma unroll
    for (int cl=0; cl<4; cl++){
      int xxo = (w*4 + cl)*16 + (lane & 15);
      #pragma unroll
      for (int q=0; q<4; q++){
        int o = rt*16 + (lane >> 4)*4 + q;     // C/D layout (m89)
        buf[o*264 + xxo] = (_Float16)(acc[rt][cl][q] + cb[o]);
      }
    }
  __syncthreads();
  {
    int o = t >> 3, xb = (t & 7)*32;
    #pragma unroll
    for (int v4=0; v4<4; v4++){
      f16x8 vv = *(const f16x8*)(buf + o*264 + xb + v4*8);
      *(f16x8*)(tout + hbase + (size_t)o*RST + xb + v4*8) = vv;
    }
  }
  if (t < CH*2){
    int oo = t >> 1, st = t & 1;
    float s = red[oo][0][st] + red[oo][1][st] + red[oo][2][st] + red[oo][3][st];
    partials[((size_t)b*HH + y)*64 + t] = s;
  }
}

// ------ deterministic stats reduce -> scale/shift (final layer only) -------
__global__ void __launch_bounds__(512) k_stats(
    const float* __restrict__ partials,
    const float* __restrict__ g, const float* __restrict__ bb,
    float* __restrict__ bnp){
  __shared__ float acc[512];
  int o = blockIdx.x, t = threadIdx.x;
  int half = t >> 8, j = t & 255;
  float s = 0.f;
  for (int k=j; k<BATCH*HH; k+=256) s += partials[(size_t)k*64 + o*2 + half];
  acc[t] = s;
  __syncthreads();
  for (int w2=128; w2>0; w2>>=1){
    if (j < w2) acc[t] += acc[t+w2];
    __syncthreads();
  }
  if (t == 0){
    const float N = (float)BATCH * (float)(HH*HH);
    float mean = acc[0] / N;
    float var  = acc[256] / N - mean*mean;
    float iv = rsqrtf(var + 1e-5f);
    float scv = g[o]*iv;
    bnp[o]      = scv;
    bnp[CH + o] = bb[o] - mean*scv;
  }
}

// ------- final MFMA: BN(l3) + fc1 + relu + fc2, quadrant only --------------
__global__ void __launch_bounds__(256) k_final(
    const _Float16* __restrict__ tb, const float* __restrict__ bnp,
    const _Float16* __restrict__ W1h, const _Float16* __restrict__ W1l,
    const float* __restrict__ b1, const float* __restrict__ w2,
    const float* __restrict__ b2, float* __restrict__ out){
  __shared__ _Float16 Vf[128][40];      // pixel-major, 80B row stride
  int yq = blockIdx.x, b = blockIdx.y, t = threadIdx.x;
  int y = (SS-1) + yq;
  size_t rbase = (size_t)(b*HH + y)*FST;
  for (int i=t; i<CH*SS; i+=256){
    int c = i >> 7, xx = i & 127;
    float v = (float)tb[rbase + (size_t)c*RST + (SS-1) + xx]
              * bnp[c] + bnp[CH+c];
    Vf[xx][c] = (_Float16)v;
  }
  __syncthreads();
  int w = t >> 6, lane = t & 63;
  int prow = lane & 15, koff = (lane >> 4)*8, col = lane & 15;
  f16x8 a0 = *(const f16x8*)&Vf[w*32 + prow][koff];
  f16x8 a1 = *(const f16x8*)&Vf[w*32 + 16 + prow][koff];
  float s0[4] = {0.f,0.f,0.f,0.f}, s1[4] = {0.f,0.f,0.f,0.f};
  #pragma unroll
  for (int nt=0; nt<8; nt++){
    f16x8 bh = *(const f16x8*)(W1h + ((size_t)nt*64 + lane)*8);
    f16x8 bl = *(const f16x8*)(W1l + ((size_t)nt*64 + lane)*8);
    f32x4 acc0 = {0.f,0.f,0.f,0.f}, acc1 = {0.f,0.f,0.f,0.f};
    acc0 = __builtin_amdgcn_mfma_f32_16x16x32_f16(a0, bh, acc0, 0,0,0);
    acc0 = __builtin_amdgcn_mfma_f32_16x16x32_f16(a0, bl, acc0, 0,0,0);
    acc1 = __builtin_amdgcn_mfma_f32_16x16x32_f16(a1, bh, acc1, 0,0,0);
    acc1 = __builtin_amdgcn_mfma_f32_16x16x32_f16(a1, bl, acc1, 0,0,0);
    float b1v = b1[nt*16 + col];
    float w2v = w2[nt*16 + col];
    #pragma unroll
    for (int q=0; q<4; q++){
      s0[q] += fmaxf(acc0[q] + b1v, 0.f)*w2v;
      s1[q] += fmaxf(acc1[q] + b1v, 0.f)*w2v;
    }
  }
  float o2b = b2[0];
  #pragma unroll
  for (int q=0; q<4; q++){
    float v0 = s0[q], v1 = s1[q];
    #pragma unroll
    for (int off=8; off>0; off>>=1){
      v0 += __shfl_xor(v0, off, 16);
      v1 += __shfl_xor(v1, off, 16);
    }
    if (col == (unsigned)q){           // one writer per pixel, deterministic
      int p0 = w*32 + (lane >> 4)*4 + q;
      int p1 = p0 + 16;
      float r0 = v0 + o2b, r1 = v1 + o2b;
      int ob = (b*DC)*SS*SS + yq*SS;
      #pragma unroll
      for (int cc=0; cc<DC; cc++){
        out[ob + cc*SS*SS + p0] = r0;
        out[ob + cc*SS*SS + p1] = r1;
      }
    }
  }
}

extern "C" void kernel_launch(void* const* d_in, const int* in_sizes, int n_in,
                              void* d_out, int out_size, void* d_ws, size_t ws_size,
                              hipStream_t stream) {
  (void)in_sizes; (void)n_in; (void)out_size; (void)ws_size;
  const float* x      = (const float*)d_in[0];
  const float* fc0_w  = (const float*)d_in[1];
  const float* fc0_b  = (const float*)d_in[2];
  const float* spec_w = (const float*)d_in[3];
  const float* conv_w = (const float*)d_in[4];
  const float* conv_b = (const float*)d_in[5];
  const float* bn_g   = (const float*)d_in[6];
  const float* bn_b   = (const float*)d_in[7];
  const float* fc1_w  = (const float*)d_in[8];
  const float* fc1_b  = (const float*)d_in[9];
  const float* fc2_w  = (const float*)d_in[10];
  const float* fc2_b  = (const float*)d_in[11];
  float* out = (float*)d_out;
  float* ws  = (float*)d_ws;

  // field: 16*255*32*256 f16 = 33,423,360 halves = 16,711,680 floats (~64 MiB)
  _Float16* field = (_Float16*)ws;
  float* Gbuf  = ws + 16711680;                        // NROWS*24 = 3,133,440
  float* Xf    = Gbuf + (size_t)NROWS*24;              // 294,912
  float* parts = Xf   + (size_t)BATCH*CH*KY24*M2*2;    // 261,120
  float* bnpF  = parts + (size_t)64*BATCH*HH;          // 64 (per-layer fuse BN)
  float* bnpL  = bnpF + 64;                            // 64 (final BN)
  _Float16* Whi = (_Float16*)(bnpL + 64);              // 8192 halves each
  _Float16* Wlo = Whi + 2*8*64*8;
  _Float16* Th  = Wlo + 2*8*64*8;
  _Float16* Tl  = Th  + 16*64*8;
  _Float16* W1h = Tl  + 16*64*8;                       // 4096 halves each
  _Float16* W1l = W1h + 8*64*8;
  _Float16* Ach = W1l + 8*64*8;                        // 8192 halves each
  _Float16* Acl = Ach + 2*8*64*8;
  _Float16* Ash = Acl + 2*8*64*8;
  _Float16* Asl = Ash + 2*8*64*8;
  _Float16* Ich = Asl + 2*8*64*8;                      // 8192 halves each
  _Float16* Icl = Ich + 16*64*8;
  _Float16* Ish = Icl + 16*64*8;
  _Float16* Isl = Ish + 16*64*8;

  k_tabs<<<26, 256, 0, stream>>>(fc1_w, Whi, Wlo, Th, Tl, W1h, W1l,
                                 Ach, Acl, Ash, Asl, Ich, Icl, Ish, Isl);
  k_fc0<<<dim3(HH, BATCH), 256, 0, stream>>>(x, fc0_w, fc0_b, field);

  const size_t wstride = (size_t)2*CH*CH*M1*M2*2;      // per-layer spec_w elems
  for (int l=0; l<4; l++){
    int l0 = (l == 0);
    int relu = (l >= 1);                               // ReLU after layers 0..2
    const float* gg = l0 ? bn_g : bn_g + (size_t)(l-1)*CH;
    const float* gb = l0 ? bn_b : bn_b + (size_t)(l-1)*CH;
    k_fwd  <<<BATCH*CH, 256, 0, stream>>>(field, Xf, Whi, Wlo,
                                          Ach, Acl, Ash, Asl,
                                          parts, gg, gb, bnpF, l0, relu);
    k_specmix<<<dim3(CH, BATCH), 256, 0, stream>>>(Xf, spec_w + (size_t)l*wstride,
                                                   Gbuf, Ich, Icl, Ish, Isl);
    k_fuse <<<dim3(HH, BATCH), 256, 0, stream>>>(field, Gbuf, conv_w + l*CH*CH,
                                                 conv_b + l*CH, field, parts,
                                                 Th, Tl, bnpF, relu);
  }
  k_stats<<<CH, 512, 0, stream>>>(parts, bn_g + 3*CH, bn_b + 3*CH, bnpL);
  k_final<<<dim3(SS, BATCH), 256, 0, stream>>>(field, bnpL, W1h, W1l,
                                               fc1_b, fc2_w, fc2_b, out);
}

// Round 23
// 420.168 us; speedup vs baseline: 1.6741x; 1.0123x over previous
//
#include <hip/hip_runtime.h>

#define BATCH 16
#define CH 32
#define DC 3
#define SS 128
#define HH 255
#define RST 256                 // padded x stride per channel (f16)
#define FST ((size_t)CH*RST)    // stride per (b,y) row-group: 8192 halves
#define M1 12
#define M2 12
#define KY24 (2*M1)
#define NROWS (BATCH*CH*HH)
#define TWOPI_N 0.02463994238463573f   // 2*pi/255

typedef __attribute__((ext_vector_type(8))) _Float16 f16x8;
typedef __attribute__((ext_vector_type(4))) float f32x4;

// field layout: [b][y][c][x]  (c-inner: k_fuse/k_final blocks contiguous)

// ------- mirror + fc0 lift, vectorized f16x8 stores ------------------------
__global__ void __launch_bounds__(256) k_fc0(
    const float* __restrict__ x, const float* __restrict__ w,
    const float* __restrict__ bias, _Float16* __restrict__ h){
  int y = blockIdx.x, b = blockIdx.y, t = threadIdx.x;
  int d = t >> 3, g = t & 7;
  int iy = (y >= SS-1) ? y - (SS-1) : (SS-1) - y;
  float w0 = w[d], w1 = w[CH+d], w2 = w[2*CH+d], bs = bias[d];
  const float* xp = x + (size_t)(b*DC)*SS*SS + iy*SS;
  size_t obase = (size_t)(b*HH + y)*FST + (size_t)d*RST;
  #pragma unroll
  for (int i=0; i<4; i++){
    int x0 = i*64 + g*8;
    f16x8 pk;
    #pragma unroll
    for (int u=0; u<8; u++){
      int xx = x0 + u;
      float v = 0.f;
      if (xx < HH){
        int ix = (xx >= SS-1) ? xx - (SS-1) : (SS-1) - xx;
        float sgn = ((y >= SS-1) == (xx >= SS-1)) ? 1.f : -1.f;
        v = bs + sgn*(xp[ix]*w0 + xp[SS*SS+ix]*w1 + xp[2*SS*SS+ix]*w2);
      }
      pk[u] = (_Float16)v;
    }
    *(f16x8*)(h + obase + x0) = pk;
  }
}

// ------- all weight/twiddle tables in one kernel ---------------------------
// 0-3: W (fwd row-DFT B)   4-7: T (fuse inv-W B)   8-9: W1 (final B)
// 10-13: Ac (fwd col-DFT A cos)  14-17: As (sin)
// 18-21: Ic (inv-H A' cos, M=y)  22-25: Is (sin)
__global__ void __launch_bounds__(256) k_tabs(
    const float* __restrict__ w1,
    _Float16* __restrict__ Whi, _Float16* __restrict__ Wlo,
    _Float16* __restrict__ Th,  _Float16* __restrict__ Tl,
    _Float16* __restrict__ W1h, _Float16* __restrict__ W1l,
    _Float16* __restrict__ Ach, _Float16* __restrict__ Acl,
    _Float16* __restrict__ Ash, _Float16* __restrict__ Asl,
    _Float16* __restrict__ Ich, _Float16* __restrict__ Icl,
    _Float16* __restrict__ Ish, _Float16* __restrict__ Isl){
  int bi = blockIdx.x;
  if (bi < 4){
    int t = bi*256 + threadIdx.x;          // t < 1024 = 2*8*64
    int ct = t >> 9, ks = (t >> 6) & 7, lane = t & 63;
    int col = ct*16 + (lane & 15);
    int kb = ks*32 + (lane >> 4)*8;
    for (int j=0; j<8; j++){
      int k = kb + j;
      float w = 0.f;
      if (k < 255 && col < 24){
        int m = col >> 1;
        float ang = TWOPI_N * (float)((k*m) % 255);
        w = (col & 1) ? -sinf(ang) : cosf(ang);
      }
      _Float16 hi = (_Float16)w;
      Whi[t*8+j] = hi;
      Wlo[t*8+j] = (_Float16)(w - (float)hi);
    }
  } else if (bi < 8){
    int t = (bi-4)*256 + threadIdx.x;      // t < 1024 = 16*64
    int ct = t >> 6, lane = t & 63;
    int xx = ct*16 + (lane & 15);
    int jbase = (lane >> 4)*8;
    for (int j=0; j<8; j++){
      int jg = jbase + j;
      float v = 0.f;
      if (xx < HH && jg <= 22){
        if (jg == 0) v = 1.f;
        else if (jg & 1){ int kx=(jg+1)>>1; v =  cosf(TWOPI_N*(float)((kx*xx)%255)); }
        else            { int kx= jg>>1;    v = -sinf(TWOPI_N*(float)((kx*xx)%255)); }
      }
      _Float16 hi = (_Float16)v;
      Th[t*8+j] = hi;
      Tl[t*8+j] = (_Float16)(v - (float)hi);
    }
  } else if (bi < 10){
    int t = (bi-8)*256 + threadIdx.x;      // t < 512 = 8*64
    int nt = t >> 6, lane = t & 63;
    int col = nt*16 + (lane & 15);
    int kb = (lane >> 4)*8;
    for (int j=0; j<8; j++){
      float v = w1[(kb+j)*128 + col];
      _Float16 hi = (_Float16)v;
      W1h[t*8+j] = hi;
      W1l[t*8+j] = (_Float16)(v - (float)hi);
    }
  } else if (bi < 14){
    int t = (bi-10)*256 + threadIdx.x;     // t < 1024 = 2*8*64
    int mt = t >> 9, ks = (t >> 6) & 7, lane = t & 63;
    int ky = mt*16 + (lane & 15);
    int yb = ks*32 + (lane >> 4)*8;
    int freq = (ky < M1) ? ky : 231 + ky;  // 0..11 / 243..254
    for (int j=0; j<8; j++){
      int yy = yb + j;
      float v = 0.f;
      if (ky < KY24 && yy < HH)
        v = cosf(TWOPI_N * (float)((freq*yy) % 255));
      _Float16 hi = (_Float16)v;
      Ach[t*8+j] = hi;
      Acl[t*8+j] = (_Float16)(v - (float)hi);
    }
  } else if (bi < 18){
    int t = (bi-14)*256 + threadIdx.x;     // t < 1024
    int mt = t >> 9, ks = (t >> 6) & 7, lane = t & 63;
    int ky = mt*16 + (lane & 15);
    int yb = ks*32 + (lane >> 4)*8;
    int freq = (ky < M1) ? ky : 231 + ky;
    for (int j=0; j<8; j++){
      int yy = yb + j;
      float v = 0.f;
      if (ky < KY24 && yy < HH)
        v = sinf(TWOPI_N * (float)((freq*yy) % 255));
      _Float16 hi = (_Float16)v;
      Ash[t*8+j] = hi;
      Asl[t*8+j] = (_Float16)(v - (float)hi);
    }
  } else if (bi < 22){
    // inverse-H A' cos: y = mt*16 + (lane&15), ky = (lane>>4)*8 + j
    int t = (bi-18)*256 + threadIdx.x;     // t < 1024 = 16*64
    int mt = t >> 6, lane = t & 63;
    int y = mt*16 + (lane & 15);
    int kb = (lane >> 4)*8;
    for (int j=0; j<8; j++){
      int ky = kb + j;
      float v = 0.f;
      if (ky < KY24 && y < HH){
        int f = (ky < M1) ? ky : ky - KY24;       // -12..-1 for ky>=12
        int m = (int)(((long)f*y) % 255); if (m < 0) m += 255;
        v = cosf(TWOPI_N * (float)m);
      }
      _Float16 hi = (_Float16)v;
      Ich[t*8+j] = hi;
      Icl[t*8+j] = (_Float16)(v - (float)hi);
    }
  } else {
    int t = (bi-22)*256 + threadIdx.x;     // t < 1024
    int mt = t >> 6, lane = t & 63;
    int y = mt*16 + (lane & 15);
    int kb = (lane >> 4)*8;
    for (int j=0; j<8; j++){
      int ky = kb + j;
      float v = 0.f;
      if (ky < KY24 && y < HH){
        int f = (ky < M1) ? ky : ky - KY24;
        int m = (int)(((long)f*y) % 255); if (m < 0) m += 255;
        v = sinf(TWOPI_N * (float)m);
      }
      _Float16 hi = (_Float16)v;
      Ish[t*8+j] = hi;
      Isl[t*8+j] = (_Float16)(v - (float)hi);
    }
  }
}

// ----- fused per-channel BN-stats + forward DFT (both axes via MFMA) -------
// lr single-f16, stride 34 (2-way banks); phase-2 = 4 MFMAs/K-step.
__global__ void __launch_bounds__(256) k_fwd(
    const _Float16* __restrict__ h, float* __restrict__ Xf,
    const _Float16* __restrict__ Whi, const _Float16* __restrict__ Wlo,
    const _Float16* __restrict__ Ach, const _Float16* __restrict__ Acl,
    const _Float16* __restrict__ Ash, const _Float16* __restrict__ Asl,
    const float* __restrict__ parts, const float* __restrict__ g,
    const float* __restrict__ bb, float* __restrict__ bnpo,
    int l0, int relu){
  __shared__ _Float16 lr[256][34];       // row-DFT out (17.4 KB, pad 34)
  float (*rs)[2] = (float(*)[2])lr;      // stats scratch aliases lr (barrier-safe)
  int t = threadIdx.x, bc = blockIdx.x;
  int wid = t >> 6, lane = t & 63;
  int c = bc & (CH-1), b = bc >> 5;
  float sc = 1.f, sh = 0.f;
  if (!l0){
    float s1 = 0.f, s2 = 0.f;
    for (int k=t; k<BATCH*HH; k+=256){
      float2 p2 = *(const float2*)(parts + (size_t)k*64 + c*2);
      s1 += p2.x; s2 += p2.y;
    }
    rs[t][0] = s1; rs[t][1] = s2;
    __syncthreads();
    for (int w2=128; w2>0; w2>>=1){
      if (t < w2){ rs[t][0] += rs[t+w2][0]; rs[t][1] += rs[t+w2][1]; }
      __syncthreads();
    }
    const float N = (float)BATCH * (float)(HH*HH);
    float mean = rs[0][0] / N;
    float var  = rs[0][1] / N - mean*mean;
    float iv = rsqrtf(var + 1e-5f);
    sc = g[c]*iv;
    sh = bb[c] - mean*sc;
    __syncthreads();                     // rs dead after this point
  }
  if (b == 0 && t == 0){ bnpo[c] = sc; bnpo[CH+c] = sh; }
  _Float16 sch = (_Float16)sc, shh = (_Float16)sh;
  f16x8 scv, shv;
  #pragma unroll
  for (int u=0; u<8; u++){ scv[u]=sch; shv[u]=shh; }
  const _Float16* base = h + (size_t)b*HH*FST + (size_t)c*RST;
  int koff = (lane >> 4)*8;
  #pragma unroll
  for (int it=0; it<4; it++){
    int y0 = it*64 + wid*16;
    int yr = y0 + (lane & 15);
    int ycl = (yr < HH) ? yr : HH-1;     // clamp pad row (output discarded)
    const _Float16* rp = base + (size_t)ycl*FST;
    f16x8 av[8];
    #pragma unroll
    for (int ks=0; ks<8; ks++)
      av[ks] = *(const f16x8*)(rp + ks*32 + koff);
    f32x4 acc0 = {0.f,0.f,0.f,0.f};
    f32x4 acc1 = {0.f,0.f,0.f,0.f};
    #pragma unroll
    for (int ks=0; ks<8; ks++){
      f16x8 a = av[ks]*scv + shv;
      if (relu){
        #pragma unroll
        for (int u=0; u<8; u++) a[u] = (a[u] > (_Float16)0.f) ? a[u] : (_Float16)0.f;
      }
      f16x8 b0h = *(const f16x8*)(Whi + ((size_t)(0*8+ks)*64 + lane)*8);
      f16x8 b0l = *(const f16x8*)(Wlo + ((size_t)(0*8+ks)*64 + lane)*8);
      f16x8 b1h = *(const f16x8*)(Whi + ((size_t)(1*8+ks)*64 + lane)*8);
      f16x8 b1l = *(const f16x8*)(Wlo + ((size_t)(1*8+ks)*64 + lane)*8);
      acc0 = __builtin_amdgcn_mfma_f32_16x16x32_f16(a, b0h, acc0, 0,0,0);
      acc0 = __builtin_amdgcn_mfma_f32_16x16x32_f16(a, b0l, acc0, 0,0,0);
      acc1 = __builtin_amdgcn_mfma_f32_16x16x32_f16(a, b1h, acc1, 0,0,0);
      acc1 = __builtin_amdgcn_mfma_f32_16x16x32_f16(a, b1l, acc1, 0,0,0);
    }
    int colq = lane & 15;
    int rq = y0 + (lane >> 4)*4;
    #pragma unroll
    for (int q=0; q<4; q++)
      if (rq+q < HH) lr[rq+q][colq] = (_Float16)acc0[q];
    if (colq < 8){
      #pragma unroll
      for (int q=0; q<4; q++)
        if (rq+q < HH) lr[rq+q][16+colq] = (_Float16)acc1[q];
    }
  }
  // zero pad row 255 (0 x NaN hazard in MFMA K-pad)
  if (t < 34) lr[255][t] = (_Float16)0.f;
  __syncthreads();
  // phase 2: column DFT via MFMA. wave w: Mtile=w>>1 (ky), Ntile=w&1 (col)
  {
    int mt = wid >> 1, nt2 = wid & 1;
    int nn = nt2*16 + (lane & 15);
    f32x4 accC = {0.f,0.f,0.f,0.f};
    f32x4 accS = {0.f,0.f,0.f,0.f};
    #pragma unroll
    for (int ks=0; ks<8; ks++){
      f16x8 bh;
      #pragma unroll
      for (int j=0; j<8; j++)
        bh[j] = lr[ks*32 + koff + j][nn];
      size_t ai = ((size_t)(mt*8 + ks)*64 + lane)*8;
      f16x8 ach = *(const f16x8*)(Ach + ai);
      f16x8 acl = *(const f16x8*)(Acl + ai);
      f16x8 ash = *(const f16x8*)(Ash + ai);
      f16x8 asl = *(const f16x8*)(Asl + ai);
      accC = __builtin_amdgcn_mfma_f32_16x16x32_f16(ach, bh, accC, 0,0,0);
      accC = __builtin_amdgcn_mfma_f32_16x16x32_f16(acl, bh, accC, 0,0,0);
      accS = __builtin_amdgcn_mfma_f32_16x16x32_f16(ash, bh, accS, 0,0,0);
      accS = __builtin_amdgcn_mfma_f32_16x16x32_f16(asl, bh, accS, 0,0,0);
    }
    const float inv = 1.0f/255.0f;
    #pragma unroll
    for (int q=0; q<4; q++){
      float d2 = __shfl_xor(accS[q], 1, 64);   // partner col (parity flip)
      float val = accC[q] + (((nn & 1) == 0) ? d2 : -d2);
      int ky = mt*16 + (lane >> 4)*4 + q;
      if (ky < KY24 && nn < 24)
        Xf[((size_t)bc*KY24 + ky)*24 + nn] = val*inv;
    }
  }
}

// --- channel-mix + inverse-H: mix (VALU) + MFMA ----------------------------
__global__ void __launch_bounds__(256) k_specmix(
    const float* __restrict__ Xf, const float* __restrict__ w,
    float* __restrict__ G,
    const _Float16* __restrict__ Ich, const _Float16* __restrict__ Icl,
    const _Float16* __restrict__ Ish, const _Float16* __restrict__ Isl){
  __shared__ _Float16 lyh[32][32];       // [ky pad32][n=2kx+c pad32], 2 KB
  __shared__ _Float16 lyl[32][32];
  int o = blockIdx.x, b = blockIdx.y, t = threadIdx.x;
  // zero pads: cols 24..31 (all rows) + rows 24..31 (cols 0..23)
  { int r = t>>3, cc = 24 + (t&7); lyh[r][cc] = (_Float16)0.f; lyl[r][cc] = (_Float16)0.f; }
  if (t < 192){ int r = 24 + t/24, cc = t%24; lyh[r][cc] = (_Float16)0.f; lyl[r][cc] = (_Float16)0.f; }
  // phase A: channel mix
  for (int m = t; m < KY24*M2; m += 256){
    int ky = m / M2, kx = m - (m/M2)*M2;
    int blk = (ky < M1) ? 0 : 1;
    int m1 = ky - blk*M1;
    const float* wp = w + (size_t)blk*(CH*CH*M1*M2*2)
                        + (size_t)o*(M1*M2*2) + m1*(M2*2) + kx*2;
    const float* xp = Xf + ((size_t)(b*CH)*KY24 + ky)*(M2*2) + kx*2;
    float ar=0.f, ai=0.f;
    for (int i=0;i<CH;i++){
      float xr = xp[0], xi = xp[1];
      float wr = wp[0], wi = wp[1];
      ar += xr*wr - xi*wi;
      ai += xr*wi + xi*wr;
      xp += KY24*M2*2;
      wp += CH*M1*M2*2;
    }
    _Float16 h1 = (_Float16)ar;
    lyh[ky][kx*2]   = h1;  lyl[ky][kx*2]   = (_Float16)(ar - (float)h1);
    _Float16 h2 = (_Float16)ai;
    lyh[ky][kx*2+1] = h2;  lyl[ky][kx*2+1] = (_Float16)(ai - (float)h2);
  }
  __syncthreads();
  // phase B: inverse-H GEMM
  int wid = t >> 6, lane = t & 63;
  int col = lane & 15, kof = (lane >> 4)*8;
  f16x8 b0h, b0l, b1h, b1l;
  #pragma unroll
  for (int j=0; j<8; j++){
    b0h[j] = lyh[kof+j][col];     b0l[j] = lyl[kof+j][col];
    b1h[j] = lyh[kof+j][16+col];  b1l[j] = lyl[kof+j][16+col];
  }
  const float inv = 1.0f/255.0f;
  size_t bo = (size_t)b*CH + o;
  float f0 = ((col >> 1) == 0) ? inv : 2.0f*inv;   // n=col -> kx=col>>1
  #pragma unroll
  for (int i=0; i<4; i++){
    int mt = wid*4 + i;
    size_t ai = ((size_t)mt*64 + lane)*8;
    f16x8 ach = *(const f16x8*)(Ich + ai);
    f16x8 acl = *(const f16x8*)(Icl + ai);
    f16x8 ash = *(const f16x8*)(Ish + ai);
    f16x8 asl = *(const f16x8*)(Isl + ai);
    f32x4 c0 = {0.f,0.f,0.f,0.f}, s0 = {0.f,0.f,0.f,0.f};
    f32x4 c1 = {0.f,0.f,0.f,0.f}, s1 = {0.f,0.f,0.f,0.f};
    c0 = __builtin_amdgcn_mfma_f32_16x16x32_f16(ach, b0h, c0, 0,0,0);
    c0 = __builtin_amdgcn_mfma_f32_16x16x32_f16(ach, b0l, c0, 0,0,0);
    c0 = __builtin_amdgcn_mfma_f32_16x16x32_f16(acl, b0h, c0, 0,0,0);
    s0 = __builtin_amdgcn_mfma_f32_16x16x32_f16(ash, b0h, s0, 0,0,0);
    s0 = __builtin_amdgcn_mfma_f32_16x16x32_f16(ash, b0l, s0, 0,0,0);
    s0 = __builtin_amdgcn_mfma_f32_16x16x32_f16(asl, b0h, s0, 0,0,0);
    c1 = __builtin_amdgcn_mfma_f32_16x16x32_f16(ach, b1h, c1, 0,0,0);
    c1 = __builtin_amdgcn_mfma_f32_16x16x32_f16(ach, b1l, c1, 0,0,0);
    c1 = __builtin_amdgcn_mfma_f32_16x16x32_f16(acl, b1h, c1, 0,0,0);
    s1 = __builtin_amdgcn_mfma_f32_16x16x32_f16(ash, b1h, s1, 0,0,0);
    s1 = __builtin_amdgcn_mfma_f32_16x16x32_f16(ash, b1l, s1, 0,0,0);
    s1 = __builtin_amdgcn_mfma_f32_16x16x32_f16(asl, b1h, s1, 0,0,0);
    #pragma unroll
    for (int q=0; q<4; q++){
      int y = mt*16 + (lane >> 4)*4 + q;
      float p0 = __shfl_xor(s0[q], 1, 64);       // partner's sin-GEMM value
      float v0 = c0[q] + ((col & 1) ? p0 : -p0); // re: C-S' ; im: S'+C
      if (y < HH) G[(bo*HH + y)*24 + col] = v0*f0;
      float p1 = __shfl_xor(s1[q], 1, 64);
      int n1 = 16 + col;
      float v1 = c1[q] + ((n1 & 1) ? p1 : -p1);
      if (y < HH && n1 < 24) G[(bo*HH + y)*24 + n1] = v1*(2.0f*inv);
    }
  }
}

// ------- fused MFMA (1 row/block): conv + inv-W + partials -----------------
__global__ void __launch_bounds__(256) k_fuse(
    const _Float16* __restrict__ h, const float* __restrict__ G,
    const float* __restrict__ cw, const float* __restrict__ cb,
    _Float16* __restrict__ tout, float* __restrict__ partials,
    const _Float16* __restrict__ Th, const _Float16* __restrict__ Tl,
    const float* __restrict__ bnp, int relu){
  __shared__ _Float16 buf[8448];   // Bf: (ct*65+lane)*8+j ; Of: o*264+xx
  __shared__ float red[CH][4][2];
  int t = threadIdx.x;
  int y = blockIdx.x, b = blockIdx.y;
  size_t hbase = (size_t)(b*HH + y)*FST;
  int cS = t >> 5, xg = t & 31;
  f16x8 ld[4];
  #pragma unroll
  for (int it=0; it<4; it++)
    ld[it] = *(const f16x8*)(h + hbase + (size_t)(it*8 + cS)*RST + xg*8);
  int w = t >> 6, lane = t & 63;
  int arow = lane & 15, koff = (lane >> 4)*8;
  f16x8 a0h[2], a0l[2], a1[2];
  #pragma unroll
  for (int rt=0; rt<2; rt++){
    int o = rt*16 + arow;
    #pragma unroll
    for (int j=0; j<8; j++){
      float v = cw[o*CH + koff + j];
      _Float16 hi = (_Float16)v;
      a0h[rt][j] = hi;
      a0l[rt][j] = (_Float16)(v - (float)hi);
    }
    const float* gp = G + ((size_t)(b*CH+o)*HH + y)*24;
    #pragma unroll
    for (int j=0; j<8; j++){
      int jg = koff + j;                 // jg>=23: T rows are zero -> don't care
      float v = (jg==0) ? gp[0] : gp[jg+1];
      a1[rt][j] = (_Float16)v;
    }
  }
  #pragma unroll
  for (int it=0; it<4; it++){
    int c = it*8 + cS;
    _Float16 sc_ = (_Float16)bnp[c], sh_ = (_Float16)bnp[CH+c];
    f16x8 scv, shv;
    #pragma unroll
    for (int u=0; u<8; u++){ scv[u]=sc_; shv[u]=sh_; }
    f16x8 z = ld[it]*scv + shv;
    if (relu){
      #pragma unroll
      for (int u=0; u<8; u++) z[u] = (z[u] > (_Float16)0.f) ? z[u] : (_Float16)0.f;
    }
    int base = ((xg>>1)*65 + ((xg&1)*8) + ((c>>3)<<4))*8 + (c&7);
    #pragma unroll
    for (int u=0; u<8; u++) buf[base + u*8] = z[u];
  }
  __syncthreads();
  f32x4 acc[2][4];
  #pragma unroll
  for (int rt=0; rt<2; rt++)
    #pragma unroll
    for (int cl=0; cl<4; cl++) acc[rt][cl] = (f32x4){0.f,0.f,0.f,0.f};
  #pragma unroll
  for (int cl=0; cl<4; cl++){
    int ct = w*4 + cl;
    f16x8 bd = *(const f16x8*)(buf + ((size_t)ct*65 + lane)*8);
    f16x8 th = *(const f16x8*)(Th + ((size_t)ct*64 + lane)*8);
    f16x8 tl = *(const f16x8*)(Tl + ((size_t)ct*64 + lane)*8);
    #pragma unroll
    for (int rt=0; rt<2; rt++){
      acc[rt][cl] = __builtin_amdgcn_mfma_f32_16x16x32_f16(a0h[rt], bd, acc[rt][cl], 0,0,0);
      acc[rt][cl] = __builtin_amdgcn_mfma_f32_16x16x32_f16(a0l[rt], bd, acc[rt][cl], 0,0,0);
      acc[rt][cl] = __builtin_amdgcn_mfma_f32_16x16x32_f16(a1[rt], th, acc[rt][cl], 0,0,0);
      acc[rt][cl] = __builtin_amdgcn_mfma_f32_16x16x32_f16(a1[rt], tl, acc[rt][cl], 0,0,0);
    }
  }
  #pragma unroll
  for (int rt=0; rt<2; rt++)
    #pragma unroll
    for (int q=0; q<4; q++){
      float v1 = 0.f, v2 = 0.f;
      #pragma unroll
      for (int cl=0; cl<4; cl++){
        int xxo = (w*4 + cl)*16 + (lane & 15);
        int o = rt*16 + (lane >> 4)*4 + q;
        float v = acc[rt][cl][q] + cb[o];
        float vv = (xxo < HH) ? v : 0.f;
        v1 += vv; v2 += vv*vv;
      }
      #pragma unroll
      for (int off=8; off>0; off>>=1){
        v1 += __shfl_xor(v1, off, 16);
        v2 += __shfl_xor(v2, off, 16);
      }
      if ((lane & 15) == 0){
        int o = rt*16 + (lane >> 4)*4 + q;
        red[o][w][0] = v1;
        red[o][w][1] = v2;
      }
    }
  __syncthreads();      // all Bf reads done -> safe to overwrite buf as Of
  #pragma unroll
  for (int rt=0; rt<2; rt++)
    #pragma unroll
    for (int cl=0; cl<4; cl++){
      int xxo = (w*4 + cl)*16 + (lane & 15);
      #pragma unroll
      for (int q=0; q<4; q++){
        int o = rt*16 + (lane >> 4)*4 + q;     // C/D layout (m89)
        buf[o*264 + xxo] = (_Float16)(acc[rt][cl][q] + cb[o]);
      }
    }
  __syncthreads();
  {
    int o = t >> 3, xb = (t & 7)*32;
    #pragma unroll
    for (int v4=0; v4<4; v4++){
      f16x8 vv = *(const f16x8*)(buf + o*264 + xb + v4*8);
      *(f16x8*)(tout + hbase + (size_t)o*RST + xb + v4*8) = vv;
    }
  }
  if (t < CH*2){
    int oo = t >> 1, st = t & 1;
    float s = red[oo][0][st] + red[oo][1][st] + red[oo][2][st] + red[oo][3][st];
    partials[((size_t)b*HH + y)*64 + t] = s;
  }
}

// ------ deterministic stats reduce -> scale/shift (final layer only) -------
__global__ void __launch_bounds__(512) k_stats(
    const float* __restrict__ partials,
    const float* __restrict__ g, const float* __restrict__ bb,
    float* __restrict__ bnp){
  __shared__ float acc[512];
  int o = blockIdx.x, t = threadIdx.x;
  int half = t >> 8, j = t & 255;
  float s = 0.f;
  for (int k=j; k<BATCH*HH; k+=256) s += partials[(size_t)k*64 + o*2 + half];
  acc[t] = s;
  __syncthreads();
  for (int w2=128; w2>0; w2>>=1){
    if (j < w2) acc[t] += acc[t+w2];
    __syncthreads();
  }
  if (t == 0){
    const float N = (float)BATCH * (float)(HH*HH);
    float mean = acc[0] / N;
    float var  = acc[256] / N - mean*mean;
    float iv = rsqrtf(var + 1e-5f);
    float scv = g[o]*iv;
    bnp[o]      = scv;
    bnp[CH + o] = bb[o] - mean*scv;
  }
}

// ------- final MFMA: BN(l3) + fc1 + relu + fc2, quadrant only --------------
__global__ void __launch_bounds__(256) k_final(
    const _Float16* __restrict__ tb, const float* __restrict__ bnp,
    const _Float16* __restrict__ W1h, const _Float16* __restrict__ W1l,
    const float* __restrict__ b1, const float* __restrict__ w2,
    const float* __restrict__ b2, float* __restrict__ out){
  __shared__ _Float16 Vf[128][40];      // pixel-major, 80B row stride
  int yq = blockIdx.x, b = blockIdx.y, t = threadIdx.x;
  int y = (SS-1) + yq;
  size_t rbase = (size_t)(b*HH + y)*FST;
  for (int i=t; i<CH*SS; i+=256){
    int c = i >> 7, xx = i & 127;
    float v = (float)tb[rbase + (size_t)c*RST + (SS-1) + xx]
              * bnp[c] + bnp[CH+c];
    Vf[xx][c] = (_Float16)v;
  }
  __syncthreads();
  int w = t >> 6, lane = t & 63;
  int prow = lane & 15, koff = (lane >> 4)*8, col = lane & 15;
  f16x8 a0 = *(const f16x8*)&Vf[w*32 + prow][koff];
  f16x8 a1 = *(const f16x8*)&Vf[w*32 + 16 + prow][koff];
  float s0[4] = {0.f,0.f,0.f,0.f}, s1[4] = {0.f,0.f,0.f,0.f};
  #pragma unroll
  for (int nt=0; nt<8; nt++){
    f16x8 bh = *(const f16x8*)(W1h + ((size_t)nt*64 + lane)*8);
    f16x8 bl = *(const f16x8*)(W1l + ((size_t)nt*64 + lane)*8);
    f32x4 acc0 = {0.f,0.f,0.f,0.f}, acc1 = {0.f,0.f,0.f,0.f};
    acc0 = __builtin_amdgcn_mfma_f32_16x16x32_f16(a0, bh, acc0, 0,0,0);
    acc0 = __builtin_amdgcn_mfma_f32_16x16x32_f16(a0, bl, acc0, 0,0,0);
    acc1 = __builtin_amdgcn_mfma_f32_16x16x32_f16(a1, bh, acc1, 0,0,0);
    acc1 = __builtin_amdgcn_mfma_f32_16x16x32_f16(a1, bl, acc1, 0,0,0);
    float b1v = b1[nt*16 + col];
    float w2v = w2[nt*16 + col];
    #pragma unroll
    for (int q=0; q<4; q++){
      s0[q] += fmaxf(acc0[q] + b1v, 0.f)*w2v;
      s1[q] += fmaxf(acc1[q] + b1v, 0.f)*w2v;
    }
  }
  float o2b = b2[0];
  #pragma unroll
  for (int q=0; q<4; q++){
    float v0 = s0[q], v1 = s1[q];
    #pragma unroll
    for (int off=8; off>0; off>>=1){
      v0 += __shfl_xor(v0, off, 16);
      v1 += __shfl_xor(v1, off, 16);
    }
    if (col == (unsigned)q){           // one writer per pixel, deterministic
      int p0 = w*32 + (lane >> 4)*4 + q;
      int p1 = p0 + 16;
      float r0 = v0 + o2b, r1 = v1 + o2b;
      int ob = (b*DC)*SS*SS + yq*SS;
      #pragma unroll
      for (int cc=0; cc<DC; cc++){
        out[ob + cc*SS*SS + p0] = r0;
        out[ob + cc*SS*SS + p1] = r1;
      }
    }
  }
}

extern "C" void kernel_launch(void* const* d_in, const int* in_sizes, int n_in,
                              void* d_out, int out_size, void* d_ws, size_t ws_size,
                              hipStream_t stream) {
  (void)in_sizes; (void)n_in; (void)out_size; (void)ws_size;
  const float* x      = (const float*)d_in[0];
  const float* fc0_w  = (const float*)d_in[1];
  const float* fc0_b  = (const float*)d_in[2];
  const float* spec_w = (const float*)d_in[3];
  const float* conv_w = (const float*)d_in[4];
  const float* conv_b = (const float*)d_in[5];
  const float* bn_g   = (const float*)d_in[6];
  const float* bn_b   = (const float*)d_in[7];
  const float* fc1_w  = (const float*)d_in[8];
  const float* fc1_b  = (const float*)d_in[9];
  const float* fc2_w  = (const float*)d_in[10];
  const float* fc2_b  = (const float*)d_in[11];
  float* out = (float*)d_out;
  float* ws  = (float*)d_ws;

  // field: 16*255*32*256 f16 = 33,423,360 halves = 16,711,680 floats (~64 MiB)
  _Float16* field = (_Float16*)ws;
  float* Gbuf  = ws + 16711680;                        // NROWS*24 = 3,133,440
  float* Xf    = Gbuf + (size_t)NROWS*24;              // 294,912
  float* parts = Xf   + (size_t)BATCH*CH*KY24*M2*2;    // 261,120
  float* bnpF  = parts + (size_t)64*BATCH*HH;          // 64 (per-layer fuse BN)
  float* bnpL  = bnpF + 64;                            // 64 (final BN)
  _Float16* Whi = (_Float16*)(bnpL + 64);              // 8192 halves each
  _Float16* Wlo = Whi + 2*8*64*8;
  _Float16* Th  = Wlo + 2*8*64*8;
  _Float16* Tl  = Th  + 16*64*8;
  _Float16* W1h = Tl  + 16*64*8;                       // 4096 halves each
  _Float16* W1l = W1h + 8*64*8;
  _Float16* Ach = W1l + 8*64*8;                        // 8192 halves each
  _Float16* Acl = Ach + 2*8*64*8;
  _Float16* Ash = Acl + 2*8*64*8;
  _Float16* Asl = Ash + 2*8*64*8;
  _Float16* Ich = Asl + 2*8*64*8;                      // 8192 halves each
  _Float16* Icl = Ich + 16*64*8;
  _Float16* Ish = Icl + 16*64*8;
  _Float16* Isl = Ish + 16*64*8;

  k_tabs<<<26, 256, 0, stream>>>(fc1_w, Whi, Wlo, Th, Tl, W1h, W1l,
                                 Ach, Acl, Ash, Asl, Ich, Icl, Ish, Isl);
  k_fc0<<<dim3(HH, BATCH), 256, 0, stream>>>(x, fc0_w, fc0_b, field);

  const size_t wstride = (size_t)2*CH*CH*M1*M2*2;      // per-layer spec_w elems
  for (int l=0; l<4; l++){
    int l0 = (l == 0);
    int relu = (l >= 1);                               // ReLU after layers 0..2
    const float* gg = l0 ? bn_g : bn_g + (size_t)(l-1)*CH;
    const float* gb = l0 ? bn_b : bn_b + (size_t)(l-1)*CH;
    k_fwd  <<<BATCH*CH, 256, 0, stream>>>(field, Xf, Whi, Wlo,
                                          Ach, Acl, Ash, Asl,
                                          parts, gg, gb, bnpF, l0, relu);
    k_specmix<<<dim3(CH, BATCH), 256, 0, stream>>>(Xf, spec_w + (size_t)l*wstride,
                                                   Gbuf, Ich, Icl, Ish, Isl);
    k_fuse <<<dim3(HH, BATCH), 256, 0, stream>>>(field, Gbuf, conv_w + l*CH*CH,
                                                 conv_b + l*CH, field, parts,
                                                 Th, Tl, bnpF, relu);
  }
  k_stats<<<CH, 512, 0, stream>>>(parts, bn_g + 3*CH, bn_b + 3*CH, bnpL);
  k_final<<<dim3(SS, BATCH), 256, 0, stream>>>(field, bnpL, W1h, W1l,
                                               fc1_b, fc2_w, fc2_b, out);
}